// Round 1
// baseline (4885.154 us; speedup 1.0000x reference)
//
#include <hip/hip_runtime.h>
#include <math.h>

// ---------------- problem constants ----------------
#define MB    512
#define FS    24
#define QDIM  11
#define OBJ   25
#define HID   256

// ---------------- conv1: 3->24, 80->40, stride2 pad1, +bias +relu ----------------
__global__ __launch_bounds__(256) void conv1_relu(
    const float* __restrict__ img, const float* __restrict__ w,
    const float* __restrict__ bias, float* __restrict__ out)
{
    int idx = blockIdx.x * 256 + threadIdx.x;           // 512*24*40*40 = 19,660,800
    int x = idx % 40; int t = idx / 40;
    int y = t % 40;   t /= 40;
    int oc = t % 24;  int b = t / 24;
    float acc = bias[oc];
    const float* wb = w + oc * 27;
    const float* ib = img + b * 3 * 6400;
#pragma unroll
    for (int ic = 0; ic < 3; ic++) {
#pragma unroll
        for (int ky = 0; ky < 3; ky++) {
            int iy = 2 * y + ky - 1;
            if ((unsigned)iy < 80u) {
#pragma unroll
                for (int kx = 0; kx < 3; kx++) {
                    int ix = 2 * x + kx - 1;
                    if ((unsigned)ix < 80u)
                        acc += ib[ic * 6400 + iy * 80 + ix] * wb[ic * 9 + ky * 3 + kx];
                }
            }
        }
    }
    out[idx] = acc > 0.f ? acc : 0.f;
}

// ---------------- generic conv: 24->24, stride2 pad1, BN(prev) on read, +bias +relu ----------------
__global__ __launch_bounds__(256) void conv_bn_relu(
    const float* __restrict__ in, const float* __restrict__ scsh,
    const float* __restrict__ w, const float* __restrict__ bias,
    float* __restrict__ out, int Hin, int Hout, int total)
{
    int idx = blockIdx.x * 256 + threadIdx.x;
    if (idx >= total) return;
    int x = idx % Hout; int t = idx / Hout;
    int y = t % Hout;   t /= Hout;
    int oc = t % 24;    int b = t / 24;
    float acc = bias[oc];
    const float* wb = w + oc * 216;
    const int hin2 = Hin * Hin;
    const float* ib = in + b * 24 * hin2;
    for (int ic = 0; ic < 24; ic++) {
        float sc = scsh[ic], sh = scsh[24 + ic];
        const float* ibc = ib + ic * hin2;
        const float* wbc = wb + ic * 9;
#pragma unroll
        for (int ky = 0; ky < 3; ky++) {
            int iy = 2 * y + ky - 1;
            if ((unsigned)iy < (unsigned)Hin) {
                const float* row = ibc + iy * Hin;
#pragma unroll
                for (int kx = 0; kx < 3; kx++) {
                    int ix = 2 * x + kx - 1;
                    if ((unsigned)ix < (unsigned)Hin)
                        acc += (row[ix] * sc + sh) * wbc[ky * 3 + kx];
                }
            }
        }
    }
    out[idx] = acc > 0.f ? acc : 0.f;
}

// ---------------- per-channel sum / sumsq over one (b,c) slab ----------------
__global__ __launch_bounds__(256) void bn_stats(
    const float* __restrict__ y, int hw, float* __restrict__ st)
{
    const int b = blockIdx.x, c = blockIdx.y;
    const float* p = y + (size_t)(b * 24 + c) * hw;
    float s = 0.f, s2 = 0.f;
    for (int i = threadIdx.x; i < hw; i += 256) { float t = p[i]; s += t; s2 += t * t; }
#pragma unroll
    for (int off = 32; off > 0; off >>= 1) {
        s  += __shfl_down(s, off, 64);
        s2 += __shfl_down(s2, off, 64);
    }
    __shared__ float ls[2];
    if (threadIdx.x == 0) { ls[0] = 0.f; ls[1] = 0.f; }
    __syncthreads();
    if ((threadIdx.x & 63) == 0) { atomicAdd(&ls[0], s); atomicAdd(&ls[1], s2); }
    __syncthreads();
    if (threadIdx.x == 0) { atomicAdd(&st[c], ls[0]); atomicAdd(&st[24 + c], ls[1]); }
}

// ---------------- BN finalize: scale = g*rsqrt(var+eps), shift = beta - mean*scale ----------------
__global__ void bn_fin(const float* __restrict__ st, const float* __restrict__ gam,
                       const float* __restrict__ bet, float invN, float* __restrict__ scsh)
{
    int c = threadIdx.x;
    if (c < 24) {
        float m   = st[c] * invN;
        float var = st[24 + c] * invN - m * m;
        float inv = gam[c] * rsqrtf(var + 1e-5f);
        scsh[c]      = inv;
        scsh[24 + c] = bet[c] - m * inv;
    }
}

// ---------------- transpose g2w/g3w/g4w [n][k] -> wt [layer][k][n] ----------------
__global__ __launch_bounds__(256) void w_transpose(
    const float* __restrict__ w2, const float* __restrict__ w3,
    const float* __restrict__ w4, float* __restrict__ wt)
{
    int idx = blockIdx.x * 256 + threadIdx.x;   // 3*65536
    int l = idx >> 16; int r = idx & 65535;
    int k = r >> 8;    int n = r & 255;
    const float* w = (l == 0) ? w2 : (l == 1 ? w3 : w4);
    wt[idx] = w[n * 256 + k];
}

// ---------------- u/v precompute for g1 ----------------
// u[b][o][n] = sum_c<26 g1w[n][c]    * xf[b][o][c]
// v[b][o][n] = sum_c<26 g1w[n][26+c] * xf[b][o][c] + sum_j g1w[n][52+j]*q[b][j] + g1b[n]
__global__ __launch_bounds__(256) void uv_kernel(
    const float* __restrict__ y4, const float* __restrict__ scsh,
    const float* __restrict__ qst, const float* __restrict__ g1w,
    const float* __restrict__ g1b, float* __restrict__ u, float* __restrict__ v)
{
    int b = blockIdx.x, tid = threadIdx.x;
    __shared__ float xf[650];    // [25][26]
    __shared__ float qv[11];
    for (int e = tid; e < 650; e += 256) {
        int o = e / 26, c = e % 26;
        float val;
        if (c < 24)      val = y4[(b * 24 + c) * 25 + o] * scsh[c] + scsh[24 + c];
        else if (c == 24) val = (float)(o / 5 - 2) * 0.5f;
        else              val = (float)(o % 5 - 2) * 0.5f;
        xf[e] = val;
    }
    if (tid < 11) qv[tid] = qst[tid * MB + b];
    __syncthreads();
    const int n = tid;
    float wrow[63];
#pragma unroll
    for (int c = 0; c < 63; c++) wrow[c] = g1w[n * 63 + c];
    float qsum = g1b[n];
#pragma unroll
    for (int j = 0; j < 11; j++) qsum += wrow[52 + j] * qv[j];
    for (int o = 0; o < 25; o++) {
        float uu = 0.f, vv = qsum;
#pragma unroll
        for (int c = 0; c < 26; c++) {
            uu += wrow[c]      * xf[o * 26 + c];
            vv += wrow[26 + c] * xf[o * 26 + c];
        }
        u[(b * 25 + o) * 256 + n] = uu;
        v[(b * 25 + o) * 256 + n] = vv;
    }
}

// ---------------- fused g2/g3/g4 + pair-sum ----------------
// Block = 32 pair-rows of one batch (20 tiles/batch, rows padded 625->640, pads masked at sum).
// h tile lives in ONE 32KB LDS buffer, layout h[f][m] with XOR-swizzled 4-row granules:
//   addr(f, m) = f*32 + ((  (m>>2) ^ (f&7) ) << 2) + (m&3)
// Each layer: full K pass reading h as X, then (post-barrier, X fully consumed) overwrite in place.
__global__ __launch_bounds__(256, 2) void g_fused(
    const float* __restrict__ u, const float* __restrict__ v,
    const float* __restrict__ wt,
    const float* __restrict__ b2, const float* __restrict__ b3, const float* __restrict__ b4,
    float* __restrict__ xg)
{
    __shared__ float hS[8192];   // 256 f x 32 m  (32KB)
    __shared__ float wS[4096];   // 16 k x 256 n  (16KB)
    const int tid = threadIdx.x;
    const int bx  = blockIdx.x;
    const int b   = bx / 20;
    const int p0  = (bx % 20) * 32;

    // ---- stage h1 = relu(u[i] + v[k]) ----
    {
        const int f  = tid & 63;
        const int mq = tid >> 6;                    // 0..3
        const float* ub = u + b * 6400;
        const float* vb = v + b * 6400;
#pragma unroll
        for (int fo = 0; fo < 4; fo++) {
            const int ff = fo * 64 + f;
#pragma unroll
            for (int gg = 0; gg < 2; gg++) {
                const int gi = mq + gg * 4;         // granule 0..7
                float val[4];
#pragma unroll
                for (int mm = 0; mm < 4; mm++) {
                    const int p = p0 + gi * 4 + mm;
                    float r = 0.f;
                    if (p < 625) {
                        const int oi = p % 25;
                        const int ok = p / 25;
                        r = ub[oi * 256 + ff] + vb[ok * 256 + ff];
                        r = r > 0.f ? r : 0.f;
                    }
                    val[mm] = r;
                }
                *(float4*)&hS[ff * 32 + ((gi ^ (ff & 7)) << 2)] =
                    make_float4(val[0], val[1], val[2], val[3]);
            }
        }
    }

    const int ng = tid & 31;
    const int mg = tid >> 5;        // 0..7
    const int n0 = ng * 4;          // cols n0..n0+3 and 128+n0..128+n0+3
    const int m0 = mg * 4;

#pragma unroll 1
    for (int layer = 0; layer < 3; layer++) {
        const float* wl = wt + layer * 65536;
        const float* bl = (layer == 0) ? b2 : (layer == 1 ? b3 : b4);
        float bias[8];
        {
            float4 t0 = *(const float4*)&bl[n0];
            float4 t1 = *(const float4*)&bl[128 + n0];
            bias[0] = t0.x; bias[1] = t0.y; bias[2] = t0.z; bias[3] = t0.w;
            bias[4] = t1.x; bias[5] = t1.y; bias[6] = t1.z; bias[7] = t1.w;
        }
        float acc[4][8];
#pragma unroll
        for (int m = 0; m < 4; m++)
#pragma unroll
            for (int j = 0; j < 8; j++) acc[m][j] = 0.f;

        float4 pf[4];
#pragma unroll
        for (int i = 0; i < 4; i++) pf[i] = *(const float4*)&wl[tid * 4 + i * 1024];

#pragma unroll 1
        for (int kb = 0; kb < 16; kb++) {
            __syncthreads();
#pragma unroll
            for (int i = 0; i < 4; i++) *(float4*)&wS[tid * 4 + i * 1024] = pf[i];
            __syncthreads();
            if (kb < 15) {
#pragma unroll
                for (int i = 0; i < 4; i++)
                    pf[i] = *(const float4*)&wl[(kb + 1) * 4096 + tid * 4 + i * 1024];
            }
#pragma unroll
            for (int kk = 0; kk < 16; kk++) {
                const int k = kb * 16 + kk;
                const float4 a4 = *(const float4*)&hS[k * 32 + ((mg ^ (kk & 7)) << 2)];
                const float4 w0 = *(const float4*)&wS[kk * 256 + n0];
                const float4 w1 = *(const float4*)&wS[kk * 256 + 128 + n0];
                const float av[4] = {a4.x, a4.y, a4.z, a4.w};
                const float wv[8] = {w0.x, w0.y, w0.z, w0.w, w1.x, w1.y, w1.z, w1.w};
#pragma unroll
                for (int m = 0; m < 4; m++)
#pragma unroll
                    for (int j = 0; j < 8; j++)
                        acc[m][j] = fmaf(av[m], wv[j], acc[m][j]);
            }
        }
        __syncthreads();   // all X reads (and wS reads) done -> safe to overwrite
        if (layer < 2) {
#pragma unroll
            for (int j = 0; j < 8; j++) {
                const int n = (j < 4) ? (n0 + j) : (128 + n0 + (j - 4));
                float e[4];
#pragma unroll
                for (int m = 0; m < 4; m++) {
                    float t = acc[m][j] + bias[j];
                    e[m] = t > 0.f ? t : 0.f;
                }
                *(float4*)&hS[n * 32 + ((mg ^ (n & 7)) << 2)] =
                    make_float4(e[0], e[1], e[2], e[3]);
            }
        } else {
            float s[8];
#pragma unroll
            for (int j = 0; j < 8; j++) s[j] = 0.f;
#pragma unroll
            for (int m = 0; m < 4; m++) {
                if (p0 + m0 + m < 625) {
#pragma unroll
                    for (int j = 0; j < 8; j++) {
                        float t = acc[m][j] + bias[j];
                        s[j] += (t > 0.f ? t : 0.f);
                    }
                }
            }
            *(float4*)&wS[mg * 256 + n0]       = make_float4(s[0], s[1], s[2], s[3]);
            *(float4*)&wS[mg * 256 + 128 + n0] = make_float4(s[4], s[5], s[6], s[7]);
            __syncthreads();
            float tot = 0.f;
#pragma unroll
            for (int g = 0; g < 8; g++) tot += wS[g * 256 + tid];
            atomicAdd(&xg[b * 256 + tid], tot);
        }
    }
}

// ---------------- f1 -> fc2 -> fc3 -> log_softmax ----------------
__global__ __launch_bounds__(256) void f_fused(
    const float* __restrict__ xg,
    const float* __restrict__ f1w, const float* __restrict__ f1b,
    const float* __restrict__ fc2w, const float* __restrict__ fc2b,
    const float* __restrict__ fc3w, const float* __restrict__ fc3b,
    float* __restrict__ out)
{
    const int b = blockIdx.x, tid = threadIdx.x;
    __shared__ float xa[256], xb[256], lg[10], red[2];
    xa[tid] = xg[b * 256 + tid];
    __syncthreads();
    {
        const float4* wr = (const float4*)(f1w + (size_t)tid * 256);
        float a = f1b[tid];
#pragma unroll
        for (int k4 = 0; k4 < 64; k4++) {
            float4 w4 = wr[k4];
            a += w4.x * xa[k4 * 4 + 0] + w4.y * xa[k4 * 4 + 1]
               + w4.z * xa[k4 * 4 + 2] + w4.w * xa[k4 * 4 + 3];
        }
        xb[tid] = a > 0.f ? a : 0.f;
    }
    __syncthreads();
    {
        const float4* wr = (const float4*)(fc2w + (size_t)tid * 256);
        float a = fc2b[tid];
#pragma unroll
        for (int k4 = 0; k4 < 64; k4++) {
            float4 w4 = wr[k4];
            a += w4.x * xb[k4 * 4 + 0] + w4.y * xb[k4 * 4 + 1]
               + w4.z * xb[k4 * 4 + 2] + w4.w * xb[k4 * 4 + 3];
        }
        __syncthreads();
        xa[tid] = a > 0.f ? a : 0.f;
    }
    __syncthreads();
    if (tid < 10) {
        const float4* wr = (const float4*)(fc3w + (size_t)tid * 256);
        float a = fc3b[tid];
#pragma unroll
        for (int k4 = 0; k4 < 64; k4++) {
            float4 w4 = wr[k4];
            a += w4.x * xa[k4 * 4 + 0] + w4.y * xa[k4 * 4 + 1]
               + w4.z * xa[k4 * 4 + 2] + w4.w * xa[k4 * 4 + 3];
        }
        lg[tid] = a;
    }
    __syncthreads();
    if (tid == 0) {
        float mx = lg[0];
        for (int o = 1; o < 10; o++) mx = lg[o] > mx ? lg[o] : mx;
        float ssum = 0.f;
        for (int o = 0; o < 10; o++) ssum += expf(lg[o] - mx);
        red[0] = mx;
        red[1] = logf(ssum);
    }
    __syncthreads();
    if (tid < 10) out[b * 10 + tid] = lg[tid] - red[0] - red[1];
}

// ---------------- launcher ----------------
extern "C" void kernel_launch(void* const* d_in, const int* in_sizes, int n_in,
                              void* d_out, int out_size, void* d_ws, size_t ws_size,
                              hipStream_t stream)
{
    const float* img  = (const float*)d_in[0];
    const float* qst  = (const float*)d_in[1];
    const float* cw1  = (const float*)d_in[2];
    const float* cb1  = (const float*)d_in[3];
    const float* bg1  = (const float*)d_in[4];
    const float* bb1  = (const float*)d_in[5];
    const float* cw2  = (const float*)d_in[6];
    const float* cb2  = (const float*)d_in[7];
    const float* bg2  = (const float*)d_in[8];
    const float* bb2  = (const float*)d_in[9];
    const float* cw3  = (const float*)d_in[10];
    const float* cb3  = (const float*)d_in[11];
    const float* bg3  = (const float*)d_in[12];
    const float* bb3  = (const float*)d_in[13];
    const float* cw4  = (const float*)d_in[14];
    const float* cb4  = (const float*)d_in[15];
    const float* bg4  = (const float*)d_in[16];
    const float* bb4  = (const float*)d_in[17];
    const float* g1w  = (const float*)d_in[18];
    const float* g1b  = (const float*)d_in[19];
    const float* g2w  = (const float*)d_in[20];
    const float* g2b  = (const float*)d_in[21];
    const float* g3w  = (const float*)d_in[22];
    const float* g3b  = (const float*)d_in[23];
    const float* g4w  = (const float*)d_in[24];
    const float* g4b  = (const float*)d_in[25];
    const float* f1w  = (const float*)d_in[26];
    const float* f1b  = (const float*)d_in[27];
    const float* fc2w = (const float*)d_in[28];
    const float* fc2b = (const float*)d_in[29];
    const float* fc3w = (const float*)d_in[30];
    const float* fc3b = (const float*)d_in[31];
    float* out = (float*)d_out;

    float* ws    = (float*)d_ws;
    float* stats = ws;                    // 4*48
    float* xg    = ws + 192;              // 512*256
    float* scsh  = ws + 131264;           // 4*48
    float* wt    = ws + 131456;           // 3*65536
    float* y1    = ws + 328064;           // 19,660,800
    float* y2    = ws + 19988864;         // 4,915,200
    float* y3    = ws + 24904064;         // 1,228,800
    float* y4    = ws + 26132864;         // 307,200
    float* u     = ws + 26440064;         // 3,276,800
    float* v     = ws + 29716864;         // 3,276,800  (end: 32,993,664 floats ~126MB)

    // zero stats + xg (ws is poisoned 0xAA before every call)
    hipMemsetAsync(stats, 0, (size_t)131264 * sizeof(float), stream);

    // transpose g2/g3/g4 weights to [k][n] (independent of convs)
    w_transpose<<<768, 256, 0, stream>>>(g2w, g3w, g4w, wt);

    // conv1
    conv1_relu<<<76800, 256, 0, stream>>>(img, cw1, cb1, y1);
    bn_stats<<<dim3(512, 24), 256, 0, stream>>>(y1, 1600, stats);
    bn_fin<<<1, 32, 0, stream>>>(stats, bg1, bb1, 1.f / 819200.f, scsh);
    // conv2
    conv_bn_relu<<<19200, 256, 0, stream>>>(y1, scsh, cw2, cb2, y2, 40, 20, 4915200);
    bn_stats<<<dim3(512, 24), 256, 0, stream>>>(y2, 400, stats + 48);
    bn_fin<<<1, 32, 0, stream>>>(stats + 48, bg2, bb2, 1.f / 204800.f, scsh + 48);
    // conv3
    conv_bn_relu<<<4800, 256, 0, stream>>>(y2, scsh + 48, cw3, cb3, y3, 20, 10, 1228800);
    bn_stats<<<dim3(512, 24), 256, 0, stream>>>(y3, 100, stats + 96);
    bn_fin<<<1, 32, 0, stream>>>(stats + 96, bg3, bb3, 1.f / 51200.f, scsh + 96);
    // conv4
    conv_bn_relu<<<1200, 256, 0, stream>>>(y3, scsh + 96, cw4, cb4, y4, 10, 5, 307200);
    bn_stats<<<dim3(512, 24), 256, 0, stream>>>(y4, 25, stats + 144);
    bn_fin<<<1, 32, 0, stream>>>(stats + 144, bg4, bb4, 1.f / 12800.f, scsh + 144);

    // g1 split into u/v
    uv_kernel<<<512, 256, 0, stream>>>(y4, scsh + 144, qst, g1w, g1b, u, v);

    // fused g2..g4 + pair sum
    g_fused<<<10240, 256, 0, stream>>>(u, v, wt, g2b, g3b, g4b, xg);

    // f-network + log_softmax
    f_fused<<<512, 256, 0, stream>>>(xg, f1w, f1b, fc2w, fc2b, fc3w, fc3b, out);
}

// Round 2
// 2599.106 us; speedup vs baseline: 1.8796x; 1.8796x over previous
//
#include <hip/hip_runtime.h>
#include <math.h>

// ---------------- problem constants ----------------
#define MB    512
#define FS    24
#define QDIM  11
#define OBJ   25
#define HID   256

typedef unsigned short u16;
typedef __attribute__((ext_vector_type(8))) __bf16 bf16x8;
typedef __attribute__((ext_vector_type(4))) float f32x4;

__device__ __forceinline__ float bf2f(u16 h) {
    return __uint_as_float(((unsigned int)h) << 16);
}
__device__ __forceinline__ u16 f2bf(float f) {
    unsigned int u = __float_as_uint(f);
    return (u16)((u + 0x7FFFu + ((u >> 16) & 1u)) >> 16);
}

// ---------------- conv1: 3->24, 80->40, stride2 pad1, +bias +relu ----------------
__global__ __launch_bounds__(256) void conv1_relu(
    const float* __restrict__ img, const float* __restrict__ w,
    const float* __restrict__ bias, float* __restrict__ out)
{
    int idx = blockIdx.x * 256 + threadIdx.x;           // 512*24*40*40 = 19,660,800
    int x = idx % 40; int t = idx / 40;
    int y = t % 40;   t /= 40;
    int oc = t % 24;  int b = t / 24;
    float acc = bias[oc];
    const float* wb = w + oc * 27;
    const float* ib = img + b * 3 * 6400;
#pragma unroll
    for (int ic = 0; ic < 3; ic++) {
#pragma unroll
        for (int ky = 0; ky < 3; ky++) {
            int iy = 2 * y + ky - 1;
            if ((unsigned)iy < 80u) {
#pragma unroll
                for (int kx = 0; kx < 3; kx++) {
                    int ix = 2 * x + kx - 1;
                    if ((unsigned)ix < 80u)
                        acc += ib[ic * 6400 + iy * 80 + ix] * wb[ic * 9 + ky * 3 + kx];
                }
            }
        }
    }
    out[idx] = acc > 0.f ? acc : 0.f;
}

// ---------------- generic conv: 24->24, stride2 pad1, BN(prev) on read, +bias +relu ----------------
__global__ __launch_bounds__(256) void conv_bn_relu(
    const float* __restrict__ in, const float* __restrict__ scsh,
    const float* __restrict__ w, const float* __restrict__ bias,
    float* __restrict__ out, int Hin, int Hout, int total)
{
    int idx = blockIdx.x * 256 + threadIdx.x;
    if (idx >= total) return;
    int x = idx % Hout; int t = idx / Hout;
    int y = t % Hout;   t /= Hout;
    int oc = t % 24;    int b = t / 24;
    float acc = bias[oc];
    const float* wb = w + oc * 216;
    const int hin2 = Hin * Hin;
    const float* ib = in + b * 24 * hin2;
    for (int ic = 0; ic < 24; ic++) {
        float sc = scsh[ic], sh = scsh[24 + ic];
        const float* ibc = ib + ic * hin2;
        const float* wbc = wb + ic * 9;
#pragma unroll
        for (int ky = 0; ky < 3; ky++) {
            int iy = 2 * y + ky - 1;
            if ((unsigned)iy < (unsigned)Hin) {
                const float* row = ibc + iy * Hin;
#pragma unroll
                for (int kx = 0; kx < 3; kx++) {
                    int ix = 2 * x + kx - 1;
                    if ((unsigned)ix < (unsigned)Hin)
                        acc += (row[ix] * sc + sh) * wbc[ky * 3 + kx];
                }
            }
        }
    }
    out[idx] = acc > 0.f ? acc : 0.f;
}

// ---------------- per-channel sum / sumsq over one (b,c) slab ----------------
__global__ __launch_bounds__(256) void bn_stats(
    const float* __restrict__ y, int hw, float* __restrict__ st)
{
    const int b = blockIdx.x, c = blockIdx.y;
    const float* p = y + (size_t)(b * 24 + c) * hw;
    float s = 0.f, s2 = 0.f;
    for (int i = threadIdx.x; i < hw; i += 256) { float t = p[i]; s += t; s2 += t * t; }
#pragma unroll
    for (int off = 32; off > 0; off >>= 1) {
        s  += __shfl_down(s, off, 64);
        s2 += __shfl_down(s2, off, 64);
    }
    __shared__ float ls[2];
    if (threadIdx.x == 0) { ls[0] = 0.f; ls[1] = 0.f; }
    __syncthreads();
    if ((threadIdx.x & 63) == 0) { atomicAdd(&ls[0], s); atomicAdd(&ls[1], s2); }
    __syncthreads();
    if (threadIdx.x == 0) { atomicAdd(&st[c], ls[0]); atomicAdd(&st[24 + c], ls[1]); }
}

// ---------------- BN finalize ----------------
__global__ void bn_fin(const float* __restrict__ st, const float* __restrict__ gam,
                       const float* __restrict__ bet, float invN, float* __restrict__ scsh)
{
    int c = threadIdx.x;
    if (c < 24) {
        float m   = st[c] * invN;
        float var = st[24 + c] * invN - m * m;
        float inv = gam[c] * rsqrtf(var + 1e-5f);
        scsh[c]      = inv;
        scsh[24 + c] = bet[c] - m * inv;
    }
}

// ---------------- w_prep: build padded bf16 LDS-image of g2w/g3w/g4w ----------------
// layout: [layer][chunk(8)][n(256)][40 halves]; halves 0..31 = W[n][chunk*32 + h], 32..39 pad
__global__ __launch_bounds__(256) void w_prep(
    const float* __restrict__ g2w, const float* __restrict__ g3w,
    const float* __restrict__ g4w, u16* __restrict__ wimg)
{
    int idx = blockIdx.x * 256 + threadIdx.x;   // 245760 total
    int l = idx / 81920; int r = idx % 81920;
    int c = r / 10240;   int rr = r % 10240;
    int n = rr / 40;     int h = rr % 40;
    const float* W = (l == 0) ? g2w : ((l == 1) ? g3w : g4w);
    u16 v = 0;
    if (h < 32) v = f2bf(W[n * 256 + c * 32 + h]);
    wimg[idx] = v;
}

// ---------------- u/v precompute for g1 (bf16 output) ----------------
__global__ __launch_bounds__(256) void uv_kernel(
    const float* __restrict__ y4, const float* __restrict__ scsh,
    const float* __restrict__ qst, const float* __restrict__ g1w,
    const float* __restrict__ g1b, u16* __restrict__ u, u16* __restrict__ v)
{
    int b = blockIdx.x, tid = threadIdx.x;
    __shared__ float xf[650];    // [25][26]
    __shared__ float qv[11];
    for (int e = tid; e < 650; e += 256) {
        int o = e / 26, c = e % 26;
        float val;
        if (c < 24)      val = y4[(b * 24 + c) * 25 + o] * scsh[c] + scsh[24 + c];
        else if (c == 24) val = (float)(o / 5 - 2) * 0.5f;
        else              val = (float)(o % 5 - 2) * 0.5f;
        xf[e] = val;
    }
    if (tid < 11) qv[tid] = qst[tid * MB + b];
    __syncthreads();
    const int n = tid;
    float wrow[63];
#pragma unroll
    for (int c = 0; c < 63; c++) wrow[c] = g1w[n * 63 + c];
    float qsum = g1b[n];
#pragma unroll
    for (int j = 0; j < 11; j++) qsum += wrow[52 + j] * qv[j];
    for (int o = 0; o < 25; o++) {
        float uu = 0.f, vv = qsum;
#pragma unroll
        for (int c = 0; c < 26; c++) {
            uu += wrow[c]      * xf[o * 26 + c];
            vv += wrow[26 + c] * xf[o * 26 + c];
        }
        u[(b * 25 + o) * 256 + n] = f2bf(uu);
        v[(b * 25 + o) * 256 + n] = f2bf(vv);
    }
}

// ---------------- fused g2/g3/g4 + pair-sum, bf16 MFMA ----------------
// Block = 128 pair-rows x N=256, 4 waves, each wave 64 rows x 128 cols.
// hS: 128 x 256 bf16, XOR-swizzled 8-half granules: addr(m, g) = m*256 + (g^(m&7))*8 halves.
// wS: one chunk image 256 n x 40 halves (k 0..31 + pad), staged via reg prefetch.
// Computes Y^T per tile: A-frag = W rows (contig k), B-frag = X rows (contig k);
// C-layout => lane holds Y[m = lane&15][n = (lane>>4)*4 + reg] per tile (4 consecutive n).
__global__ __launch_bounds__(256, 1) void g_fused(
    const u16* __restrict__ u_bf, const u16* __restrict__ v_bf,
    const u16* __restrict__ wimg,
    const float* __restrict__ b2, const float* __restrict__ b3, const float* __restrict__ b4,
    float* __restrict__ xg)
{
    __shared__ u16 hS[32768];   // 64KB
    __shared__ u16 wS[10240];   // 20KB
    const int tid  = threadIdx.x;
    const int b    = blockIdx.x / 5;
    const int p0   = (blockIdx.x % 5) * 128;
    const int lane = tid & 63, wave = tid >> 6;
    const int r16  = lane & 15, sub = lane >> 4;       // sub: 0..3
    const int m0w  = (wave & 1) * 64;
    const int n0w  = (wave >> 1) * 128;

    // prefetch layer0 chunk0 weight image into regs
    uint4 pf[5];
    {
        const uint4* s = (const uint4*)wimg;
#pragma unroll
        for (int j = 0; j < 5; j++) pf[j] = s[j * 256 + tid];
    }

    // ---- stage h1 = relu(u[oi] + v[ok]) into hS (bf16, swizzled) ----
    {
        const int m = tid & 127, half = tid >> 7;
        const int p = p0 + m;
        if (p < 625) {
            const int oi = p % 25, ok = p / 25;
            const uint4* up = (const uint4*)(u_bf + (size_t)(b * 25 + oi) * 256);
            const uint4* vp = (const uint4*)(v_bf + (size_t)(b * 25 + ok) * 256);
#pragma unroll
            for (int gi = 0; gi < 16; gi++) {
                const int g = half * 16 + gi;
                uint4 ua = up[g], va = vp[g];
                const u16* uh = (const u16*)&ua;
                const u16* vh = (const u16*)&va;
                u16 o[8];
#pragma unroll
                for (int i = 0; i < 8; i++) {
                    float f = bf2f(uh[i]) + bf2f(vh[i]);
                    f = f > 0.f ? f : 0.f;
                    o[i] = f2bf(f);
                }
                *(uint4*)&hS[m * 256 + ((g ^ (m & 7)) * 8)] = *(uint4*)o;
            }
        } else {
            uint4 z = make_uint4(0, 0, 0, 0);
#pragma unroll
            for (int gi = 0; gi < 16; gi++) {
                const int g = half * 16 + gi;
                *(uint4*)&hS[m * 256 + ((g ^ (m & 7)) * 8)] = z;
            }
        }
    }

#pragma unroll 1
    for (int l = 0; l < 3; l++) {
        f32x4 acc[4][8];
#pragma unroll
        for (int tm = 0; tm < 4; tm++)
#pragma unroll
            for (int tn = 0; tn < 8; tn++)
                acc[tm][tn] = (f32x4)(0.f);

#pragma unroll 1
        for (int kb = 0; kb < 8; kb++) {
            __syncthreads();    // prev reads of wS done / hS staged (l==0,kb==0)
            // store prefetched chunk to LDS (contiguous: conflict-free)
#pragma unroll
            for (int j = 0; j < 5; j++)
                *(uint4*)&wS[tid * 8 + j * 2048] = pf[j];
            // prefetch next chunk (overlaps with compute below)
            {
                int nl = l, nc = kb + 1;
                if (kb == 7) { nl = l + 1; nc = 0; }
                if (nl < 3) {
                    const uint4* s = (const uint4*)(wimg + (size_t)(nl * 8 + nc) * 10240);
#pragma unroll
                    for (int j = 0; j < 5; j++) pf[j] = s[j * 256 + tid];
                }
            }
            __syncthreads();    // wS visible

            bf16x8 bfr[4], afr[8];
            const int sw = kb * 4 + sub;
#pragma unroll
            for (int tm = 0; tm < 4; tm++) {
                const int m = m0w + tm * 16 + r16;
                bfr[tm] = *(const bf16x8*)&hS[m * 256 + ((sw ^ (m & 7)) * 8)];
            }
#pragma unroll
            for (int tn = 0; tn < 8; tn++) {
                const int n = n0w + tn * 16 + r16;
                afr[tn] = *(const bf16x8*)&wS[n * 40 + sub * 8];
            }
#pragma unroll
            for (int tn = 0; tn < 8; tn++)
#pragma unroll
                for (int tm = 0; tm < 4; tm++)
                    acc[tm][tn] = __builtin_amdgcn_mfma_f32_16x16x32_bf16(
                        afr[tn], bfr[tm], acc[tm][tn], 0, 0, 0);
        }
        __syncthreads();    // all hS reads complete before overwrite / final reduce

        const float* bl = (l == 0) ? b2 : ((l == 1) ? b3 : b4);
        if (l < 2) {
            // epilogue: relu(acc+bias) -> bf16 -> hS in place
#pragma unroll
            for (int tn = 0; tn < 8; tn++) {
                const int n0 = n0w + tn * 16 + sub * 4;
                const float4 bb = *(const float4*)&bl[n0];
                const int gg = n0 >> 3;
                const int sh = (sub & 1) * 4;
#pragma unroll
                for (int tm = 0; tm < 4; tm++) {
                    const int m = m0w + tm * 16 + r16;
                    u16 o[4];
                    o[0] = f2bf(fmaxf(acc[tm][tn][0] + bb.x, 0.f));
                    o[1] = f2bf(fmaxf(acc[tm][tn][1] + bb.y, 0.f));
                    o[2] = f2bf(fmaxf(acc[tm][tn][2] + bb.z, 0.f));
                    o[3] = f2bf(fmaxf(acc[tm][tn][3] + bb.w, 0.f));
                    *(ushort4*)&hS[m * 256 + ((gg ^ (m & 7)) * 8) + sh] = *(ushort4*)o;
                }
            }
            // next layer's first __syncthreads() guards these writes
        } else {
            // final: masked pair-sum -> cross-lane reduce -> atomicAdd
            float s[8][4];
#pragma unroll
            for (int tn = 0; tn < 8; tn++)
#pragma unroll
                for (int r = 0; r < 4; r++) s[tn][r] = 0.f;
#pragma unroll
            for (int tn = 0; tn < 8; tn++) {
                const int n0 = n0w + tn * 16 + sub * 4;
                const float4 bb = *(const float4*)&bl[n0];
#pragma unroll
                for (int tm = 0; tm < 4; tm++) {
                    const int m = m0w + tm * 16 + r16;
                    if (p0 + m < 625) {
                        s[tn][0] += fmaxf(acc[tm][tn][0] + bb.x, 0.f);
                        s[tn][1] += fmaxf(acc[tm][tn][1] + bb.y, 0.f);
                        s[tn][2] += fmaxf(acc[tm][tn][2] + bb.z, 0.f);
                        s[tn][3] += fmaxf(acc[tm][tn][3] + bb.w, 0.f);
                    }
                }
            }
#pragma unroll
            for (int tn = 0; tn < 8; tn++)
#pragma unroll
                for (int r = 0; r < 4; r++) {
                    float v = s[tn][r];
                    v += __shfl_xor(v, 1, 64);
                    v += __shfl_xor(v, 2, 64);
                    v += __shfl_xor(v, 4, 64);
                    v += __shfl_xor(v, 8, 64);
                    if (r16 == 0)
                        atomicAdd(&xg[b * 256 + n0w + tn * 16 + sub * 4 + r], v);
                }
        }
    }
}

// ---------------- f1 -> fc2 -> fc3 -> log_softmax ----------------
__global__ __launch_bounds__(256) void f_fused(
    const float* __restrict__ xg,
    const float* __restrict__ f1w, const float* __restrict__ f1b,
    const float* __restrict__ fc2w, const float* __restrict__ fc2b,
    const float* __restrict__ fc3w, const float* __restrict__ fc3b,
    float* __restrict__ out)
{
    const int b = blockIdx.x, tid = threadIdx.x;
    __shared__ float xa[256], xb[256], lg[10], red[2];
    xa[tid] = xg[b * 256 + tid];
    __syncthreads();
    {
        const float4* wr = (const float4*)(f1w + (size_t)tid * 256);
        float a = f1b[tid];
#pragma unroll
        for (int k4 = 0; k4 < 64; k4++) {
            float4 w4 = wr[k4];
            a += w4.x * xa[k4 * 4 + 0] + w4.y * xa[k4 * 4 + 1]
               + w4.z * xa[k4 * 4 + 2] + w4.w * xa[k4 * 4 + 3];
        }
        xb[tid] = a > 0.f ? a : 0.f;
    }
    __syncthreads();
    {
        const float4* wr = (const float4*)(fc2w + (size_t)tid * 256);
        float a = fc2b[tid];
#pragma unroll
        for (int k4 = 0; k4 < 64; k4++) {
            float4 w4 = wr[k4];
            a += w4.x * xb[k4 * 4 + 0] + w4.y * xb[k4 * 4 + 1]
               + w4.z * xb[k4 * 4 + 2] + w4.w * xb[k4 * 4 + 3];
        }
        __syncthreads();
        xa[tid] = a > 0.f ? a : 0.f;
    }
    __syncthreads();
    if (tid < 10) {
        const float4* wr = (const float4*)(fc3w + (size_t)tid * 256);
        float a = fc3b[tid];
#pragma unroll
        for (int k4 = 0; k4 < 64; k4++) {
            float4 w4 = wr[k4];
            a += w4.x * xa[k4 * 4 + 0] + w4.y * xa[k4 * 4 + 1]
               + w4.z * xa[k4 * 4 + 2] + w4.w * xa[k4 * 4 + 3];
        }
        lg[tid] = a;
    }
    __syncthreads();
    if (tid == 0) {
        float mx = lg[0];
        for (int o = 1; o < 10; o++) mx = lg[o] > mx ? lg[o] : mx;
        float ssum = 0.f;
        for (int o = 0; o < 10; o++) ssum += expf(lg[o] - mx);
        red[0] = mx;
        red[1] = logf(ssum);
    }
    __syncthreads();
    if (tid < 10) out[b * 10 + tid] = lg[tid] - red[0] - red[1];
}

// ---------------- launcher ----------------
extern "C" void kernel_launch(void* const* d_in, const int* in_sizes, int n_in,
                              void* d_out, int out_size, void* d_ws, size_t ws_size,
                              hipStream_t stream)
{
    const float* img  = (const float*)d_in[0];
    const float* qst  = (const float*)d_in[1];
    const float* cw1  = (const float*)d_in[2];
    const float* cb1  = (const float*)d_in[3];
    const float* bg1  = (const float*)d_in[4];
    const float* bb1  = (const float*)d_in[5];
    const float* cw2  = (const float*)d_in[6];
    const float* cb2  = (const float*)d_in[7];
    const float* bg2  = (const float*)d_in[8];
    const float* bb2  = (const float*)d_in[9];
    const float* cw3  = (const float*)d_in[10];
    const float* cb3  = (const float*)d_in[11];
    const float* bg3  = (const float*)d_in[12];
    const float* bb3  = (const float*)d_in[13];
    const float* cw4  = (const float*)d_in[14];
    const float* cb4  = (const float*)d_in[15];
    const float* bg4  = (const float*)d_in[16];
    const float* bb4  = (const float*)d_in[17];
    const float* g1w  = (const float*)d_in[18];
    const float* g1b  = (const float*)d_in[19];
    const float* g2w  = (const float*)d_in[20];
    const float* g2b  = (const float*)d_in[21];
    const float* g3w  = (const float*)d_in[22];
    const float* g3b  = (const float*)d_in[23];
    const float* g4w  = (const float*)d_in[24];
    const float* g4b  = (const float*)d_in[25];
    const float* f1w  = (const float*)d_in[26];
    const float* f1b  = (const float*)d_in[27];
    const float* fc2w = (const float*)d_in[28];
    const float* fc2b = (const float*)d_in[29];
    const float* fc3w = (const float*)d_in[30];
    const float* fc3b = (const float*)d_in[31];
    float* out = (float*)d_out;

    float* ws    = (float*)d_ws;
    float* stats = ws;                        // 192
    float* xg    = ws + 192;                  // 131072
    float* scsh  = ws + 131264;               // 192
    u16*   wimg  = (u16*)(ws + 131456);       // 245760 u16 (fits old wt region)
    float* y1    = ws + 328064;               // 19,660,800
    float* y2    = ws + 19988864;             // 4,915,200
    float* y3    = ws + 24904064;             // 1,228,800
    float* y4    = ws + 26132864;             // 307,200
    u16*   u_bf  = (u16*)(ws + 26440064);     // 3,276,800 u16
    u16*   v_bf  = (u16*)(ws + 28078464);     // 3,276,800 u16

    // zero stats + xg
    hipMemsetAsync(stats, 0, (size_t)131264 * sizeof(float), stream);

    // bf16 weight image for g2/g3/g4 (independent of convs)
    w_prep<<<960, 256, 0, stream>>>(g2w, g3w, g4w, wimg);

    // conv1
    conv1_relu<<<76800, 256, 0, stream>>>(img, cw1, cb1, y1);
    bn_stats<<<dim3(512, 24), 256, 0, stream>>>(y1, 1600, stats);
    bn_fin<<<1, 32, 0, stream>>>(stats, bg1, bb1, 1.f / 819200.f, scsh);
    // conv2
    conv_bn_relu<<<19200, 256, 0, stream>>>(y1, scsh, cw2, cb2, y2, 40, 20, 4915200);
    bn_stats<<<dim3(512, 24), 256, 0, stream>>>(y2, 400, stats + 48);
    bn_fin<<<1, 32, 0, stream>>>(stats + 48, bg2, bb2, 1.f / 204800.f, scsh + 48);
    // conv3
    conv_bn_relu<<<4800, 256, 0, stream>>>(y2, scsh + 48, cw3, cb3, y3, 20, 10, 1228800);
    bn_stats<<<dim3(512, 24), 256, 0, stream>>>(y3, 100, stats + 96);
    bn_fin<<<1, 32, 0, stream>>>(stats + 96, bg3, bb3, 1.f / 51200.f, scsh + 96);
    // conv4
    conv_bn_relu<<<1200, 256, 0, stream>>>(y3, scsh + 96, cw4, cb4, y4, 10, 5, 307200);
    bn_stats<<<dim3(512, 24), 256, 0, stream>>>(y4, 25, stats + 144);
    bn_fin<<<1, 32, 0, stream>>>(stats + 144, bg4, bb4, 1.f / 12800.f, scsh + 144);

    // g1 split into u/v (bf16)
    uv_kernel<<<512, 256, 0, stream>>>(y4, scsh + 144, qst, g1w, g1b, u_bf, v_bf);

    // fused g2..g4 + pair sum (bf16 MFMA)
    g_fused<<<2560, 256, 0, stream>>>(u_bf, v_bf, wimg, g2b, g3b, g4b, xg);

    // f-network + log_softmax
    f_fused<<<512, 256, 0, stream>>>(xg, f1w, f1b, fc2w, fc2b, fc3w, fc3b, out);
}

// Round 3
// 1018.324 us; speedup vs baseline: 4.7973x; 2.5523x over previous
//
#include <hip/hip_runtime.h>
#include <math.h>

// ---------------- problem constants ----------------
#define MB    512
#define FS    24
#define QDIM  11
#define OBJ   25
#define HID   256

typedef unsigned short u16;
typedef __attribute__((ext_vector_type(8))) __bf16 bf16x8;
typedef __attribute__((ext_vector_type(4))) float f32x4;

__device__ __forceinline__ float bf2f(u16 h) {
    return __uint_as_float(((unsigned int)h) << 16);
}
__device__ __forceinline__ u16 f2bf(float f) {
    unsigned int u = __float_as_uint(f);
    return (u16)((u + 0x7FFFu + ((u >> 16) & 1u)) >> 16);
}

// ---------------- conv weight prep ----------------
// wt1[k][oc] (27x24) from cw1 [24][3][3][3]
// wtc[l][kk 9][g 6][oc 24][j 4] = cw[oc][g*4+j][ky][kx], l in {conv2,conv3,conv4}
__global__ __launch_bounds__(256) void wc_prep(
    const float* __restrict__ cw1, const float* __restrict__ cw2,
    const float* __restrict__ cw3, const float* __restrict__ cw4,
    float* __restrict__ wt1, float* __restrict__ wtc)
{
    int idx = blockIdx.x * 256 + threadIdx.x;
    if (idx < 648) {
        int k = idx / 24, oc = idx % 24;
        wt1[idx] = cw1[oc * 27 + k];
    } else if (idx < 648 + 15552) {
        int t = idx - 648;
        int l = t / 5184, r = t % 5184;
        int j = r % 4, oc = (r / 4) % 24, g = (r / 96) % 6, kk = r / 576;
        const float* w = (l == 0) ? cw2 : ((l == 1) ? cw3 : cw4);
        wtc[t] = w[oc * 216 + (g * 4 + j) * 9 + kk];
    }
}

// ---------------- conv1: img NCHW -> y1_t channel-last, + fused BN stats ----------------
__global__ __launch_bounds__(256) void conv1_t(
    const float* __restrict__ img, const float* __restrict__ wt1,
    const float* __restrict__ bias, float* __restrict__ yout,
    float* __restrict__ stats)
{
    __shared__ float tile[3 * 21 * 85];   // [ic][iy 21][ixt 85(pad odd)]
    __shared__ float part[48];
    const int tid = threadIdx.x;
    const int b   = blockIdx.x >> 2;
    const int y0  = (blockIdx.x & 3) * 10;
    const int iy_base = 2 * y0 - 1;
    for (int e = tid; e < 3 * 21 * 85; e += 256) {
        int ixt = e % 85; int rem = e / 85;
        int iyl = rem % 21; int ic = rem / 21;
        int iy = iy_base + iyl, ix = ixt - 1;
        float v = 0.f;
        if ((unsigned)iy < 80u && (unsigned)ix < 80u)
            v = img[((size_t)(b * 3 + ic) * 80 + iy) * 80 + ix];
        tile[e] = v;
    }
    if (tid < 48) part[tid] = 0.f;
    __syncthreads();

    float rsum[24], rsq[24];
#pragma unroll
    for (int oc = 0; oc < 24; oc++) { rsum[oc] = 0.f; rsq[oc] = 0.f; }

#pragma unroll 1
    for (int pp = 0; pp < 2; pp++) {
        const int pxl = tid + pp * 256;
        const bool active = pxl < 400;
        const int pxc = active ? pxl : 0;
        const int yl = pxc / 40, x = pxc % 40;
        float acc[24];
#pragma unroll
        for (int oc = 0; oc < 24; oc++) acc[oc] = bias[oc];
#pragma unroll 1
        for (int ic = 0; ic < 3; ic++) {
#pragma unroll 1
            for (int ky = 0; ky < 3; ky++) {
#pragma unroll 1
                for (int kx = 0; kx < 3; kx++) {
                    const int k = (ic * 3 + ky) * 3 + kx;
                    float xin = tile[ic * 1785 + (2 * yl + ky) * 85 + (2 * x + kx)];
                    const float4* wrow = (const float4*)&wt1[k * 24];
#pragma unroll
                    for (int g = 0; g < 6; g++) {
                        float4 wv = wrow[g];
                        acc[g * 4 + 0] = fmaf(xin, wv.x, acc[g * 4 + 0]);
                        acc[g * 4 + 1] = fmaf(xin, wv.y, acc[g * 4 + 1]);
                        acc[g * 4 + 2] = fmaf(xin, wv.z, acc[g * 4 + 2]);
                        acc[g * 4 + 3] = fmaf(xin, wv.w, acc[g * 4 + 3]);
                    }
                }
            }
        }
#pragma unroll
        for (int oc = 0; oc < 24; oc++)
            acc[oc] = active ? fmaxf(acc[oc], 0.f) : 0.f;
        if (active) {
            float* op = &yout[((size_t)b * 1600 + (y0 + yl) * 40 + x) * 24];
#pragma unroll
            for (int g = 0; g < 6; g++)
                *(float4*)&op[g * 4] = make_float4(acc[g * 4], acc[g * 4 + 1],
                                                   acc[g * 4 + 2], acc[g * 4 + 3]);
        }
#pragma unroll
        for (int oc = 0; oc < 24; oc++) {
            rsum[oc] += acc[oc];
            rsq[oc]  += acc[oc] * acc[oc];
        }
    }
#pragma unroll
    for (int oc = 0; oc < 24; oc++) {
        float a = rsum[oc], q = rsq[oc];
#pragma unroll
        for (int off = 1; off < 64; off <<= 1) {
            a += __shfl_xor(a, off, 64);
            q += __shfl_xor(q, off, 64);
        }
        if ((tid & 63) == 0) { atomicAdd(&part[oc], a); atomicAdd(&part[24 + oc], q); }
    }
    __syncthreads();
    if (tid < 48) atomicAdd(&stats[tid], part[tid]);
}

// ---------------- generic conv 24->24 stride2 pad1, channel-last, BN(prev) folded on read,
//                  + fused BN stats of own output ----------------
template<int HIN, int HOUT, int YT>
__global__ __launch_bounds__(256) void convN(
    const float* __restrict__ yin,   // [b][HIN*HIN][24]
    const float* __restrict__ scsh,  // 48 (prev layer BN)
    const float* __restrict__ wtc,   // [9][6][24][4]
    const float* __restrict__ bias,  // 24
    float* __restrict__ yout,        // [b][HOUT*HOUT][24]
    float* __restrict__ stats)       // 48
{
    constexpr int ROWS  = 2 * YT + 1;
    constexpr int R     = 2 * HOUT + 3;     // odd row length (bank-parity shift)
    constexpr int TSZ   = ROWS * R * 25;    // ic padded to 25
    constexpr int NPX   = HOUT * HOUT;
    constexpr int TILES = HOUT / YT;
    __shared__ float tile[TSZ];
    __shared__ float part[48];
    const int tid = threadIdx.x;
    const int b   = (TILES == 1) ? blockIdx.x : (int)(blockIdx.x / TILES);
    const int y0  = (TILES == 1) ? 0 : (int)(blockIdx.x % TILES) * YT;
    const int iy_base = 2 * y0 - 1;

    for (int e = tid; e < TSZ; e += 256) {
        int ic = e % 25; int rem = e / 25;
        int ixt = rem % R; int iyl = rem / R;
        int iy = iy_base + iyl, ix = ixt - 1;
        float v = 0.f;
        if (ic < 24 && (unsigned)iy < (unsigned)HIN && (unsigned)ix < (unsigned)HIN)
            v = yin[((size_t)b * HIN * HIN + iy * HIN + ix) * 24 + ic] * scsh[ic] + scsh[24 + ic];
        tile[e] = v;
    }
    if (tid < 48) part[tid] = 0.f;
    __syncthreads();

    const bool active = tid < YT * HOUT;
    const int pxc = active ? tid : 0;
    const int yl = pxc / HOUT, x = pxc % HOUT;

    float acc[24];
#pragma unroll
    for (int oc = 0; oc < 24; oc++) acc[oc] = bias[oc];

#pragma unroll 1
    for (int ky = 0; ky < 3; ky++) {
#pragma unroll 1
        for (int kx = 0; kx < 3; kx++) {
            const int kk = ky * 3 + kx;
            const float* trow = &tile[((2 * yl + ky) * R + (2 * x + kx)) * 25];
            const float4* wrow = (const float4*)&wtc[kk * 576];
#pragma unroll
            for (int g = 0; g < 6; g++) {
                float x0 = trow[g * 4 + 0], x1 = trow[g * 4 + 1];
                float x2 = trow[g * 4 + 2], x3 = trow[g * 4 + 3];
#pragma unroll
                for (int oc = 0; oc < 24; oc++) {
                    float4 wv = wrow[g * 24 + oc];
                    acc[oc] = fmaf(x0, wv.x, acc[oc]);
                    acc[oc] = fmaf(x1, wv.y, acc[oc]);
                    acc[oc] = fmaf(x2, wv.z, acc[oc]);
                    acc[oc] = fmaf(x3, wv.w, acc[oc]);
                }
            }
        }
    }
#pragma unroll
    for (int oc = 0; oc < 24; oc++)
        acc[oc] = active ? fmaxf(acc[oc], 0.f) : 0.f;
    if (active) {
        const int px = (y0 + yl) * HOUT + x;
        float* op = &yout[((size_t)b * NPX + px) * 24];
#pragma unroll
        for (int g = 0; g < 6; g++)
            *(float4*)&op[g * 4] = make_float4(acc[g * 4], acc[g * 4 + 1],
                                               acc[g * 4 + 2], acc[g * 4 + 3]);
    }
#pragma unroll
    for (int oc = 0; oc < 24; oc++) {
        float a = acc[oc], q = acc[oc] * acc[oc];
#pragma unroll
        for (int off = 1; off < 64; off <<= 1) {
            a += __shfl_xor(a, off, 64);
            q += __shfl_xor(q, off, 64);
        }
        if ((tid & 63) == 0) { atomicAdd(&part[oc], a); atomicAdd(&part[24 + oc], q); }
    }
    __syncthreads();
    if (tid < 48) atomicAdd(&stats[tid], part[tid]);
}

// ---------------- BN finalize ----------------
__global__ void bn_fin(const float* __restrict__ st, const float* __restrict__ gam,
                       const float* __restrict__ bet, float invN, float* __restrict__ scsh)
{
    int c = threadIdx.x;
    if (c < 24) {
        float m   = st[c] * invN;
        float var = st[24 + c] * invN - m * m;
        float inv = gam[c] * rsqrtf(var + 1e-5f);
        scsh[c]      = inv;
        scsh[24 + c] = bet[c] - m * inv;
    }
}

// ---------------- w_prep: padded bf16 image of g2w/g3w/g4w ----------------
// layout: [layer][chunk(8)][n(256)][40 halves]; halves 0..31 = W[n][chunk*32+h], 32..39 pad
__global__ __launch_bounds__(256) void w_prep(
    const float* __restrict__ g2w, const float* __restrict__ g3w,
    const float* __restrict__ g4w, u16* __restrict__ wimg)
{
    int idx = blockIdx.x * 256 + threadIdx.x;   // 245760 total
    int l = idx / 81920; int r = idx % 81920;
    int c = r / 10240;   int rr = r % 10240;
    int n = rr / 40;     int h = rr % 40;
    const float* W = (l == 0) ? g2w : ((l == 1) ? g3w : g4w);
    u16 v = 0;
    if (h < 32) v = f2bf(W[n * 256 + c * 32 + h]);
    wimg[idx] = v;
}

// ---------------- u/v precompute for g1 (bf16 output) ----------------
__global__ __launch_bounds__(256) void uv_kernel(
    const float* __restrict__ y4t, const float* __restrict__ scsh,
    const float* __restrict__ qst, const float* __restrict__ g1w,
    const float* __restrict__ g1b, u16* __restrict__ u, u16* __restrict__ v)
{
    int b = blockIdx.x, tid = threadIdx.x;
    __shared__ float xf[650];    // [25][26]
    __shared__ float qv[11];
    for (int e = tid; e < 650; e += 256) {
        int o = e / 26, c = e % 26;
        float val;
        if (c < 24)      val = y4t[b * 600 + o * 24 + c] * scsh[c] + scsh[24 + c];
        else if (c == 24) val = (float)(o / 5 - 2) * 0.5f;
        else              val = (float)(o % 5 - 2) * 0.5f;
        xf[e] = val;
    }
    if (tid < 11) qv[tid] = qst[tid * MB + b];
    __syncthreads();
    const int n = tid;
    float wrow[63];
#pragma unroll
    for (int c = 0; c < 63; c++) wrow[c] = g1w[n * 63 + c];
    float qsum = g1b[n];
#pragma unroll
    for (int j = 0; j < 11; j++) qsum += wrow[52 + j] * qv[j];
    for (int o = 0; o < 25; o++) {
        float uu = 0.f, vv = qsum;
#pragma unroll
        for (int c = 0; c < 26; c++) {
            uu += wrow[c]      * xf[o * 26 + c];
            vv += wrow[26 + c] * xf[o * 26 + c];
        }
        u[(b * 25 + o) * 256 + n] = f2bf(uu);
        v[(b * 25 + o) * 256 + n] = f2bf(vv);
    }
}

// ---------------- fused g2/g3/g4 + pair-sum, bf16 MFMA ----------------
__global__ __launch_bounds__(256, 1) void g_fused(
    const u16* __restrict__ u_bf, const u16* __restrict__ v_bf,
    const u16* __restrict__ wimg,
    const float* __restrict__ b2, const float* __restrict__ b3, const float* __restrict__ b4,
    float* __restrict__ xg)
{
    __shared__ u16 hS[32768];   // 64KB  128 rows x 256, swizzled 8-half granules
    __shared__ u16 wS[10240];   // 20KB  256 n x 40 halves
    const int tid  = threadIdx.x;
    const int b    = blockIdx.x / 5;
    const int p0   = (blockIdx.x % 5) * 128;
    const int lane = tid & 63, wave = tid >> 6;
    const int r16  = lane & 15, sub = lane >> 4;
    const int m0w  = (wave & 1) * 64;
    const int n0w  = (wave >> 1) * 128;

    uint4 pf[5];
    {
        const uint4* s = (const uint4*)wimg;
#pragma unroll
        for (int j = 0; j < 5; j++) pf[j] = s[j * 256 + tid];
    }

    {
        const int m = tid & 127, half = tid >> 7;
        const int p = p0 + m;
        if (p < 625) {
            const int oi = p % 25, ok = p / 25;
            const uint4* up = (const uint4*)(u_bf + (size_t)(b * 25 + oi) * 256);
            const uint4* vp = (const uint4*)(v_bf + (size_t)(b * 25 + ok) * 256);
#pragma unroll
            for (int gi = 0; gi < 16; gi++) {
                const int g = half * 16 + gi;
                uint4 ua = up[g], va = vp[g];
                const u16* uh = (const u16*)&ua;
                const u16* vh = (const u16*)&va;
                u16 o[8];
#pragma unroll
                for (int i = 0; i < 8; i++) {
                    float f = bf2f(uh[i]) + bf2f(vh[i]);
                    f = f > 0.f ? f : 0.f;
                    o[i] = f2bf(f);
                }
                *(uint4*)&hS[m * 256 + ((g ^ (m & 7)) * 8)] = *(uint4*)o;
            }
        } else {
            uint4 z = make_uint4(0, 0, 0, 0);
#pragma unroll
            for (int gi = 0; gi < 16; gi++) {
                const int g = half * 16 + gi;
                *(uint4*)&hS[m * 256 + ((g ^ (m & 7)) * 8)] = z;
            }
        }
    }

#pragma unroll 1
    for (int l = 0; l < 3; l++) {
        f32x4 acc[4][8];
#pragma unroll
        for (int tm = 0; tm < 4; tm++)
#pragma unroll
            for (int tn = 0; tn < 8; tn++)
                acc[tm][tn] = (f32x4)(0.f);

#pragma unroll 1
        for (int kb = 0; kb < 8; kb++) {
            __syncthreads();
#pragma unroll
            for (int j = 0; j < 5; j++)
                *(uint4*)&wS[tid * 8 + j * 2048] = pf[j];
            {
                int nl = l, nc = kb + 1;
                if (kb == 7) { nl = l + 1; nc = 0; }
                if (nl < 3) {
                    const uint4* s = (const uint4*)(wimg + (size_t)(nl * 8 + nc) * 10240);
#pragma unroll
                    for (int j = 0; j < 5; j++) pf[j] = s[j * 256 + tid];
                }
            }
            __syncthreads();

            bf16x8 bfr[4], afr[8];
            const int sw = kb * 4 + sub;
#pragma unroll
            for (int tm = 0; tm < 4; tm++) {
                const int m = m0w + tm * 16 + r16;
                bfr[tm] = *(const bf16x8*)&hS[m * 256 + ((sw ^ (m & 7)) * 8)];
            }
#pragma unroll
            for (int tn = 0; tn < 8; tn++) {
                const int n = n0w + tn * 16 + r16;
                afr[tn] = *(const bf16x8*)&wS[n * 40 + sub * 8];
            }
#pragma unroll
            for (int tn = 0; tn < 8; tn++)
#pragma unroll
                for (int tm = 0; tm < 4; tm++)
                    acc[tm][tn] = __builtin_amdgcn_mfma_f32_16x16x32_bf16(
                        afr[tn], bfr[tm], acc[tm][tn], 0, 0, 0);
        }
        __syncthreads();

        const float* bl = (l == 0) ? b2 : ((l == 1) ? b3 : b4);
        if (l < 2) {
#pragma unroll
            for (int tn = 0; tn < 8; tn++) {
                const int n0 = n0w + tn * 16 + sub * 4;
                const float4 bb = *(const float4*)&bl[n0];
                const int gg = n0 >> 3;
                const int sh = (sub & 1) * 4;
#pragma unroll
                for (int tm = 0; tm < 4; tm++) {
                    const int m = m0w + tm * 16 + r16;
                    u16 o[4];
                    o[0] = f2bf(fmaxf(acc[tm][tn][0] + bb.x, 0.f));
                    o[1] = f2bf(fmaxf(acc[tm][tn][1] + bb.y, 0.f));
                    o[2] = f2bf(fmaxf(acc[tm][tn][2] + bb.z, 0.f));
                    o[3] = f2bf(fmaxf(acc[tm][tn][3] + bb.w, 0.f));
                    *(ushort4*)&hS[m * 256 + ((gg ^ (m & 7)) * 8) + sh] = *(ushort4*)o;
                }
            }
        } else {
            float s[8][4];
#pragma unroll
            for (int tn = 0; tn < 8; tn++)
#pragma unroll
                for (int r = 0; r < 4; r++) s[tn][r] = 0.f;
#pragma unroll
            for (int tn = 0; tn < 8; tn++) {
                const int n0 = n0w + tn * 16 + sub * 4;
                const float4 bb = *(const float4*)&bl[n0];
#pragma unroll
                for (int tm = 0; tm < 4; tm++) {
                    const int m = m0w + tm * 16 + r16;
                    if (p0 + m < 625) {
                        s[tn][0] += fmaxf(acc[tm][tn][0] + bb.x, 0.f);
                        s[tn][1] += fmaxf(acc[tm][tn][1] + bb.y, 0.f);
                        s[tn][2] += fmaxf(acc[tm][tn][2] + bb.z, 0.f);
                        s[tn][3] += fmaxf(acc[tm][tn][3] + bb.w, 0.f);
                    }
                }
            }
#pragma unroll
            for (int tn = 0; tn < 8; tn++)
#pragma unroll
                for (int r = 0; r < 4; r++) {
                    float v = s[tn][r];
                    v += __shfl_xor(v, 1, 64);
                    v += __shfl_xor(v, 2, 64);
                    v += __shfl_xor(v, 4, 64);
                    v += __shfl_xor(v, 8, 64);
                    if (r16 == 0)
                        atomicAdd(&xg[b * 256 + n0w + tn * 16 + sub * 4 + r], v);
                }
        }
    }
}

// ---------------- f1 -> fc2 -> fc3 -> log_softmax ----------------
__global__ __launch_bounds__(256) void f_fused(
    const float* __restrict__ xg,
    const float* __restrict__ f1w, const float* __restrict__ f1b,
    const float* __restrict__ fc2w, const float* __restrict__ fc2b,
    const float* __restrict__ fc3w, const float* __restrict__ fc3b,
    float* __restrict__ out)
{
    const int b = blockIdx.x, tid = threadIdx.x;
    __shared__ float xa[256], xb[256], lg[10], red[2];
    xa[tid] = xg[b * 256 + tid];
    __syncthreads();
    {
        const float4* wr = (const float4*)(f1w + (size_t)tid * 256);
        float a = f1b[tid];
#pragma unroll
        for (int k4 = 0; k4 < 64; k4++) {
            float4 w4 = wr[k4];
            a += w4.x * xa[k4 * 4 + 0] + w4.y * xa[k4 * 4 + 1]
               + w4.z * xa[k4 * 4 + 2] + w4.w * xa[k4 * 4 + 3];
        }
        xb[tid] = a > 0.f ? a : 0.f;
    }
    __syncthreads();
    {
        const float4* wr = (const float4*)(fc2w + (size_t)tid * 256);
        float a = fc2b[tid];
#pragma unroll
        for (int k4 = 0; k4 < 64; k4++) {
            float4 w4 = wr[k4];
            a += w4.x * xb[k4 * 4 + 0] + w4.y * xb[k4 * 4 + 1]
               + w4.z * xb[k4 * 4 + 2] + w4.w * xb[k4 * 4 + 3];
        }
        __syncthreads();
        xa[tid] = a > 0.f ? a : 0.f;
    }
    __syncthreads();
    if (tid < 10) {
        const float4* wr = (const float4*)(fc3w + (size_t)tid * 256);
        float a = fc3b[tid];
#pragma unroll
        for (int k4 = 0; k4 < 64; k4++) {
            float4 w4 = wr[k4];
            a += w4.x * xa[k4 * 4 + 0] + w4.y * xa[k4 * 4 + 1]
               + w4.z * xa[k4 * 4 + 2] + w4.w * xa[k4 * 4 + 3];
        }
        lg[tid] = a;
    }
    __syncthreads();
    if (tid == 0) {
        float mx = lg[0];
        for (int o = 1; o < 10; o++) mx = lg[o] > mx ? lg[o] : mx;
        float ssum = 0.f;
        for (int o = 0; o < 10; o++) ssum += expf(lg[o] - mx);
        red[0] = mx;
        red[1] = logf(ssum);
    }
    __syncthreads();
    if (tid < 10) out[b * 10 + tid] = lg[tid] - red[0] - red[1];
}

// ---------------- launcher ----------------
extern "C" void kernel_launch(void* const* d_in, const int* in_sizes, int n_in,
                              void* d_out, int out_size, void* d_ws, size_t ws_size,
                              hipStream_t stream)
{
    const float* img  = (const float*)d_in[0];
    const float* qst  = (const float*)d_in[1];
    const float* cw1  = (const float*)d_in[2];
    const float* cb1  = (const float*)d_in[3];
    const float* bg1  = (const float*)d_in[4];
    const float* bb1  = (const float*)d_in[5];
    const float* cw2  = (const float*)d_in[6];
    const float* cb2  = (const float*)d_in[7];
    const float* bg2  = (const float*)d_in[8];
    const float* bb2  = (const float*)d_in[9];
    const float* cw3  = (const float*)d_in[10];
    const float* cb3  = (const float*)d_in[11];
    const float* bg3  = (const float*)d_in[12];
    const float* bb3  = (const float*)d_in[13];
    const float* cw4  = (const float*)d_in[14];
    const float* cb4  = (const float*)d_in[15];
    const float* bg4  = (const float*)d_in[16];
    const float* bb4  = (const float*)d_in[17];
    const float* g1w  = (const float*)d_in[18];
    const float* g1b  = (const float*)d_in[19];
    const float* g2w  = (const float*)d_in[20];
    const float* g2b  = (const float*)d_in[21];
    const float* g3w  = (const float*)d_in[22];
    const float* g3b  = (const float*)d_in[23];
    const float* g4w  = (const float*)d_in[24];
    const float* g4b  = (const float*)d_in[25];
    const float* f1w  = (const float*)d_in[26];
    const float* f1b  = (const float*)d_in[27];
    const float* fc2w = (const float*)d_in[28];
    const float* fc2b = (const float*)d_in[29];
    const float* fc3w = (const float*)d_in[30];
    const float* fc3b = (const float*)d_in[31];
    float* out = (float*)d_out;

    float* ws    = (float*)d_ws;
    float* stats = ws;                        // 192
    float* xg    = ws + 192;                  // 131072
    float* scsh  = ws + 131264;               // 192
    u16*   wimg  = (u16*)(ws + 131456);       // 245760 u16
    float* y1    = ws + 328064;               // 19,660,800  [b][1600][24]
    float* y2    = ws + 19988864;             // 4,915,200   [b][400][24]
    float* y3    = ws + 24904064;             // 1,228,800   [b][100][24]
    float* y4    = ws + 26132864;             // 307,200     [b][25][24]
    u16*   u_bf  = (u16*)(ws + 26440064);     // 3,276,800 u16
    u16*   v_bf  = (u16*)(ws + 28078464);     // 3,276,800 u16
    float* wt1   = ws + 29716864;             // 648
    float* wtc   = ws + 29717512;             // 15552

    hipMemsetAsync(stats, 0, (size_t)131264 * sizeof(float), stream);

    w_prep<<<960, 256, 0, stream>>>(g2w, g3w, g4w, wimg);
    wc_prep<<<64, 256, 0, stream>>>(cw1, cw2, cw3, cw4, wt1, wtc);

    conv1_t<<<2048, 256, 0, stream>>>(img, wt1, cb1, y1, stats);
    bn_fin<<<1, 32, 0, stream>>>(stats, bg1, bb1, 1.f / 819200.f, scsh);

    convN<40, 20, 10><<<1024, 256, 0, stream>>>(y1, scsh, wtc, cb2, y2, stats + 48);
    bn_fin<<<1, 32, 0, stream>>>(stats + 48, bg2, bb2, 1.f / 204800.f, scsh + 48);

    convN<20, 10, 10><<<512, 256, 0, stream>>>(y2, scsh + 48, wtc + 5184, cb3, y3, stats + 96);
    bn_fin<<<1, 32, 0, stream>>>(stats + 96, bg3, bb3, 1.f / 51200.f, scsh + 96);

    convN<10, 5, 5><<<512, 256, 0, stream>>>(y3, scsh + 96, wtc + 10368, cb4, y4, stats + 144);
    bn_fin<<<1, 32, 0, stream>>>(stats + 144, bg4, bb4, 1.f / 12800.f, scsh + 144);

    uv_kernel<<<512, 256, 0, stream>>>(y4, scsh + 144, qst, g1w, g1b, u_bf, v_bf);

    g_fused<<<2560, 256, 0, stream>>>(u_bf, v_bf, wimg, g2b, g3b, g4b, xg);

    f_fused<<<512, 256, 0, stream>>>(xg, f1w, f1b, fc2w, fc2b, fc3w, fc3b, out);
}

// Round 4
// 800.871 us; speedup vs baseline: 6.0998x; 1.2715x over previous
//
#include <hip/hip_runtime.h>
#include <math.h>

// ---------------- problem constants ----------------
#define MB    512
#define FS    24
#define QDIM  11
#define OBJ   25
#define HID   256

typedef unsigned short u16;
typedef __attribute__((ext_vector_type(8))) __bf16 bf16x8;
typedef __attribute__((ext_vector_type(4))) float f32x4;

__device__ __forceinline__ float bf2f(u16 h) {
    return __uint_as_float(((unsigned int)h) << 16);
}
__device__ __forceinline__ u16 f2bf(float f) {
    unsigned int u = __float_as_uint(f);
    return (u16)((u + 0x7FFFu + ((u >> 16) & 1u)) >> 16);
}

// ---------------- conv weight prep ----------------
__global__ __launch_bounds__(256) void wc_prep(
    const float* __restrict__ cw1, const float* __restrict__ cw2,
    const float* __restrict__ cw3, const float* __restrict__ cw4,
    float* __restrict__ wt1, float* __restrict__ wtc)
{
    int idx = blockIdx.x * 256 + threadIdx.x;
    if (idx < 648) {
        int k = idx / 24, oc = idx % 24;
        wt1[idx] = cw1[oc * 27 + k];
    } else if (idx < 648 + 15552) {
        int t = idx - 648;
        int l = t / 5184, r = t % 5184;
        int j = r % 4, oc = (r / 4) % 24, g = (r / 96) % 6, kk = r / 576;
        const float* w = (l == 0) ? cw2 : ((l == 1) ? cw3 : cw4);
        wtc[t] = w[oc * 216 + (g * 4 + j) * 9 + kk];
    }
}

// ---------------- conv1: img NCHW -> y1 channel-last, + fused BN stats ----------------
__global__ __launch_bounds__(256) void conv1_t(
    const float* __restrict__ img, const float* __restrict__ wt1,
    const float* __restrict__ bias, float* __restrict__ yout,
    float* __restrict__ stats)
{
    __shared__ float tile[3 * 21 * 85];
    __shared__ float part[48];
    const int tid = threadIdx.x;
    const int b   = blockIdx.x >> 2;
    const int y0  = (blockIdx.x & 3) * 10;
    const int iy_base = 2 * y0 - 1;
    for (int e = tid; e < 3 * 21 * 85; e += 256) {
        int ixt = e % 85; int rem = e / 85;
        int iyl = rem % 21; int ic = rem / 21;
        int iy = iy_base + iyl, ix = ixt - 1;
        float v = 0.f;
        if ((unsigned)iy < 80u && (unsigned)ix < 80u)
            v = img[((size_t)(b * 3 + ic) * 80 + iy) * 80 + ix];
        tile[e] = v;
    }
    if (tid < 48) part[tid] = 0.f;
    __syncthreads();

    float rsum[24], rsq[24];
#pragma unroll
    for (int oc = 0; oc < 24; oc++) { rsum[oc] = 0.f; rsq[oc] = 0.f; }

#pragma unroll 1
    for (int pp = 0; pp < 2; pp++) {
        const int pxl = tid + pp * 256;
        const bool active = pxl < 400;
        const int pxc = active ? pxl : 0;
        const int yl = pxc / 40, x = pxc % 40;
        float acc[24];
#pragma unroll
        for (int oc = 0; oc < 24; oc++) acc[oc] = bias[oc];
#pragma unroll 1
        for (int ic = 0; ic < 3; ic++) {
#pragma unroll 1
            for (int ky = 0; ky < 3; ky++) {
#pragma unroll 1
                for (int kx = 0; kx < 3; kx++) {
                    const int k = (ic * 3 + ky) * 3 + kx;
                    float xin = tile[ic * 1785 + (2 * yl + ky) * 85 + (2 * x + kx)];
                    const float4* wrow = (const float4*)&wt1[k * 24];
#pragma unroll
                    for (int g = 0; g < 6; g++) {
                        float4 wv = wrow[g];
                        acc[g * 4 + 0] = fmaf(xin, wv.x, acc[g * 4 + 0]);
                        acc[g * 4 + 1] = fmaf(xin, wv.y, acc[g * 4 + 1]);
                        acc[g * 4 + 2] = fmaf(xin, wv.z, acc[g * 4 + 2]);
                        acc[g * 4 + 3] = fmaf(xin, wv.w, acc[g * 4 + 3]);
                    }
                }
            }
        }
#pragma unroll
        for (int oc = 0; oc < 24; oc++)
            acc[oc] = active ? fmaxf(acc[oc], 0.f) : 0.f;
        if (active) {
            float* op = &yout[((size_t)b * 1600 + (y0 + yl) * 40 + x) * 24];
#pragma unroll
            for (int g = 0; g < 6; g++)
                *(float4*)&op[g * 4] = make_float4(acc[g * 4], acc[g * 4 + 1],
                                                   acc[g * 4 + 2], acc[g * 4 + 3]);
        }
#pragma unroll
        for (int oc = 0; oc < 24; oc++) {
            rsum[oc] += acc[oc];
            rsq[oc]  += acc[oc] * acc[oc];
        }
    }
#pragma unroll
    for (int oc = 0; oc < 24; oc++) {
        float a = rsum[oc], q = rsq[oc];
#pragma unroll
        for (int off = 1; off < 64; off <<= 1) {
            a += __shfl_xor(a, off, 64);
            q += __shfl_xor(q, off, 64);
        }
        if ((tid & 63) == 0) { atomicAdd(&part[oc], a); atomicAdd(&part[24 + oc], q); }
    }
    __syncthreads();
    if (tid < 48) atomicAdd(&stats[tid], part[tid]);
}

// ---------------- generic conv 24->24, channel-last, BN folded on read + fused stats ----------------
template<int HIN, int HOUT, int YT>
__global__ __launch_bounds__(256) void convN(
    const float* __restrict__ yin,
    const float* __restrict__ scsh,
    const float* __restrict__ wtc,
    const float* __restrict__ bias,
    float* __restrict__ yout,
    float* __restrict__ stats)
{
    constexpr int ROWS  = 2 * YT + 1;
    constexpr int R     = 2 * HOUT + 3;
    constexpr int TSZ   = ROWS * R * 25;
    constexpr int NPX   = HOUT * HOUT;
    constexpr int TILES = HOUT / YT;
    __shared__ float tile[TSZ];
    __shared__ float part[48];
    const int tid = threadIdx.x;
    const int b   = (TILES == 1) ? blockIdx.x : (int)(blockIdx.x / TILES);
    const int y0  = (TILES == 1) ? 0 : (int)(blockIdx.x % TILES) * YT;
    const int iy_base = 2 * y0 - 1;

    for (int e = tid; e < TSZ; e += 256) {
        int ic = e % 25; int rem = e / 25;
        int ixt = rem % R; int iyl = rem / R;
        int iy = iy_base + iyl, ix = ixt - 1;
        float v = 0.f;
        if (ic < 24 && (unsigned)iy < (unsigned)HIN && (unsigned)ix < (unsigned)HIN)
            v = yin[((size_t)b * HIN * HIN + iy * HIN + ix) * 24 + ic] * scsh[ic] + scsh[24 + ic];
        tile[e] = v;
    }
    if (tid < 48) part[tid] = 0.f;
    __syncthreads();

    const bool active = tid < YT * HOUT;
    const int pxc = active ? tid : 0;
    const int yl = pxc / HOUT, x = pxc % HOUT;

    float acc[24];
#pragma unroll
    for (int oc = 0; oc < 24; oc++) acc[oc] = bias[oc];

#pragma unroll 1
    for (int ky = 0; ky < 3; ky++) {
#pragma unroll 1
        for (int kx = 0; kx < 3; kx++) {
            const int kk = ky * 3 + kx;
            const float* trow = &tile[((2 * yl + ky) * R + (2 * x + kx)) * 25];
            const float4* wrow = (const float4*)&wtc[kk * 576];
#pragma unroll
            for (int g = 0; g < 6; g++) {
                float x0 = trow[g * 4 + 0], x1 = trow[g * 4 + 1];
                float x2 = trow[g * 4 + 2], x3 = trow[g * 4 + 3];
#pragma unroll
                for (int oc = 0; oc < 24; oc++) {
                    float4 wv = wrow[g * 24 + oc];
                    acc[oc] = fmaf(x0, wv.x, acc[oc]);
                    acc[oc] = fmaf(x1, wv.y, acc[oc]);
                    acc[oc] = fmaf(x2, wv.z, acc[oc]);
                    acc[oc] = fmaf(x3, wv.w, acc[oc]);
                }
            }
        }
    }
#pragma unroll
    for (int oc = 0; oc < 24; oc++)
        acc[oc] = active ? fmaxf(acc[oc], 0.f) : 0.f;
    if (active) {
        const int px = (y0 + yl) * HOUT + x;
        float* op = &yout[((size_t)b * NPX + px) * 24];
#pragma unroll
        for (int g = 0; g < 6; g++)
            *(float4*)&op[g * 4] = make_float4(acc[g * 4], acc[g * 4 + 1],
                                               acc[g * 4 + 2], acc[g * 4 + 3]);
    }
#pragma unroll
    for (int oc = 0; oc < 24; oc++) {
        float a = acc[oc], q = acc[oc] * acc[oc];
#pragma unroll
        for (int off = 1; off < 64; off <<= 1) {
            a += __shfl_xor(a, off, 64);
            q += __shfl_xor(q, off, 64);
        }
        if ((tid & 63) == 0) { atomicAdd(&part[oc], a); atomicAdd(&part[24 + oc], q); }
    }
    __syncthreads();
    if (tid < 48) atomicAdd(&stats[tid], part[tid]);
}

// ---------------- BN finalize ----------------
__global__ void bn_fin(const float* __restrict__ st, const float* __restrict__ gam,
                       const float* __restrict__ bet, float invN, float* __restrict__ scsh)
{
    int c = threadIdx.x;
    if (c < 24) {
        float m   = st[c] * invN;
        float var = st[24 + c] * invN - m * m;
        float inv = gam[c] * rsqrtf(var + 1e-5f);
        scsh[c]      = inv;
        scsh[24 + c] = bet[c] - m * inv;
    }
}

// ---------------- w_prep: per-lane MFMA A-fragment image of g2w/g3w/g4w ----------------
// wfrag[step=l*8+c][tn 16][lane 64][jj 8]  (u16 bf16):
//   n = tn*16 + (lane&15), k = c*32 + (lane>>4)*8 + jj, val = W[n][k]
__global__ __launch_bounds__(256) void w_prep(
    const float* __restrict__ g2w, const float* __restrict__ g3w,
    const float* __restrict__ g4w, u16* __restrict__ wfrag)
{
    int idx = blockIdx.x * 256 + threadIdx.x;   // 196608 total
    int jj = idx & 7;
    int lane = (idx >> 3) & 63;
    int tn = (idx >> 9) & 15;
    int c = (idx >> 13) & 7;
    int l = idx >> 16;
    const float* W = (l == 0) ? g2w : ((l == 1) ? g3w : g4w);
    int n = tn * 16 + (lane & 15);
    int k = c * 32 + (lane >> 4) * 8 + jj;
    wfrag[idx] = f2bf(W[n * 256 + k]);
}

// ---------------- u/v precompute for g1 (bf16 output) ----------------
__global__ __launch_bounds__(256) void uv_kernel(
    const float* __restrict__ y4t, const float* __restrict__ scsh,
    const float* __restrict__ qst, const float* __restrict__ g1w,
    const float* __restrict__ g1b, u16* __restrict__ u, u16* __restrict__ v)
{
    int b = blockIdx.x, tid = threadIdx.x;
    __shared__ float xf[650];
    __shared__ float qv[11];
    for (int e = tid; e < 650; e += 256) {
        int o = e / 26, c = e % 26;
        float val;
        if (c < 24)      val = y4t[b * 600 + o * 24 + c] * scsh[c] + scsh[24 + c];
        else if (c == 24) val = (float)(o / 5 - 2) * 0.5f;
        else              val = (float)(o % 5 - 2) * 0.5f;
        xf[e] = val;
    }
    if (tid < 11) qv[tid] = qst[tid * MB + b];
    __syncthreads();
    const int n = tid;
    float wrow[63];
#pragma unroll
    for (int c = 0; c < 63; c++) wrow[c] = g1w[n * 63 + c];
    float qsum = g1b[n];
#pragma unroll
    for (int j = 0; j < 11; j++) qsum += wrow[52 + j] * qv[j];
    for (int o = 0; o < 25; o++) {
        float uu = 0.f, vv = qsum;
#pragma unroll
        for (int c = 0; c < 26; c++) {
            uu += wrow[c]      * xf[o * 26 + c];
            vv += wrow[26 + c] * xf[o * 26 + c];
        }
        u[(b * 25 + o) * 256 + n] = f2bf(uu);
        v[(b * 25 + o) * 256 + n] = f2bf(vv);
    }
}

// ---------------- fused g2/g3/g4 + pair-sum, bf16 MFMA, weights direct-from-global ----------------
// Block = 128 pair-rows x N=256; 4 waves, wave tile 128m x 64n (n0w = wave*64).
// hS only in LDS (64KB) -> 2 blocks/CU. Weight A-frags loaded from pre-permuted
// global image (L2-resident), software-pipelined one chunk ahead. 2 barriers/layer.
__global__ __launch_bounds__(256, 2) void g_fused(
    const u16* __restrict__ u_bf, const u16* __restrict__ v_bf,
    const u16* __restrict__ wfrag,
    const float* __restrict__ b2, const float* __restrict__ b3, const float* __restrict__ b4,
    float* __restrict__ xg)
{
    __shared__ u16 hS[32768];   // 128 x 256 halves, XOR-swizzled 8-half granules
    const int tid  = threadIdx.x;
    const int b    = blockIdx.x / 5;
    const int p0   = (blockIdx.x % 5) * 128;
    const int lane = tid & 63, wave = tid >> 6;
    const int r16  = lane & 15, sub = lane >> 4;
    const int n0w  = wave * 64;

    // per-lane weight fragment base (halves)
    const u16* wfL = wfrag + (size_t)(wave * 4) * 512 + (size_t)lane * 8;

    bf16x8 wcur[4], wnxt[4];
#pragma unroll
    for (int tn = 0; tn < 4; tn++)
        wcur[tn] = *(const bf16x8*)&wfL[(size_t)tn * 512];
#pragma unroll
    for (int tn = 0; tn < 4; tn++) wnxt[tn] = wcur[tn];

    // ---- stage h1 = relu(u[oi] + v[ok]) into hS ----
    {
        const int m = tid & 127, half = tid >> 7;
        const int p = p0 + m;
        if (p < 625) {
            const int oi = p % 25, ok = p / 25;
            const uint4* up = (const uint4*)(u_bf + (size_t)(b * 25 + oi) * 256);
            const uint4* vp = (const uint4*)(v_bf + (size_t)(b * 25 + ok) * 256);
#pragma unroll
            for (int gi = 0; gi < 16; gi++) {
                const int g = half * 16 + gi;
                uint4 ua = up[g], va = vp[g];
                const u16* uh = (const u16*)&ua;
                const u16* vh = (const u16*)&va;
                u16 o[8];
#pragma unroll
                for (int i = 0; i < 8; i++) {
                    float f = bf2f(uh[i]) + bf2f(vh[i]);
                    f = f > 0.f ? f : 0.f;
                    o[i] = f2bf(f);
                }
                *(uint4*)&hS[m * 256 + ((g ^ (m & 7)) * 8)] = *(uint4*)o;
            }
        } else {
            uint4 z = make_uint4(0, 0, 0, 0);
#pragma unroll
            for (int gi = 0; gi < 16; gi++) {
                const int g = half * 16 + gi;
                *(uint4*)&hS[m * 256 + ((g ^ (m & 7)) * 8)] = z;
            }
        }
    }

#pragma unroll 1
    for (int l = 0; l < 3; l++) {
        f32x4 acc[8][4];
#pragma unroll
        for (int tm = 0; tm < 8; tm++)
#pragma unroll
            for (int tn = 0; tn < 4; tn++)
                acc[tm][tn] = (f32x4)(0.f);

        __syncthreads();   // hS ready (staging or previous epilogue)

#pragma unroll 1
        for (int kb = 0; kb < 8; kb++) {
            const int s = l * 8 + kb;
            // prefetch next chunk's weight fragments (global, L2-resident)
            if (s < 23) {
#pragma unroll
                for (int tn = 0; tn < 4; tn++)
                    wnxt[tn] = *(const bf16x8*)&wfL[((size_t)(s + 1) * 16 + tn) * 512];
            }
            bf16x8 bfr[8];
            const int g = kb * 4 + sub;
#pragma unroll
            for (int tm = 0; tm < 8; tm++) {
                const int m = tm * 16 + r16;
                bfr[tm] = *(const bf16x8*)&hS[m * 256 + ((g ^ (m & 7)) * 8)];
            }
#pragma unroll
            for (int tm = 0; tm < 8; tm++)
#pragma unroll
                for (int tn = 0; tn < 4; tn++)
                    acc[tm][tn] = __builtin_amdgcn_mfma_f32_16x16x32_bf16(
                        wcur[tn], bfr[tm], acc[tm][tn], 0, 0, 0);
#pragma unroll
            for (int tn = 0; tn < 4; tn++) wcur[tn] = wnxt[tn];
        }
        __syncthreads();   // all hS reads complete before overwrite

        const float* bl = (l == 0) ? b2 : ((l == 1) ? b3 : b4);
        if (l < 2) {
#pragma unroll
            for (int tn = 0; tn < 4; tn++) {
                const int n0 = n0w + tn * 16 + sub * 4;
                const float4 bb = *(const float4*)&bl[n0];
                const int gg = n0 >> 3;
                const int sh = (sub & 1) * 4;
#pragma unroll
                for (int tm = 0; tm < 8; tm++) {
                    const int m = tm * 16 + r16;
                    u16 o[4];
                    o[0] = f2bf(fmaxf(acc[tm][tn][0] + bb.x, 0.f));
                    o[1] = f2bf(fmaxf(acc[tm][tn][1] + bb.y, 0.f));
                    o[2] = f2bf(fmaxf(acc[tm][tn][2] + bb.z, 0.f));
                    o[3] = f2bf(fmaxf(acc[tm][tn][3] + bb.w, 0.f));
                    *(ushort4*)&hS[m * 256 + ((gg ^ (m & 7)) * 8) + sh] = *(ushort4*)o;
                }
            }
        } else {
            float s[4][4];
#pragma unroll
            for (int tn = 0; tn < 4; tn++)
#pragma unroll
                for (int r = 0; r < 4; r++) s[tn][r] = 0.f;
#pragma unroll
            for (int tn = 0; tn < 4; tn++) {
                const int n0 = n0w + tn * 16 + sub * 4;
                const float4 bb = *(const float4*)&bl[n0];
#pragma unroll
                for (int tm = 0; tm < 8; tm++) {
                    const int m = tm * 16 + r16;
                    if (p0 + m < 625) {
                        s[tn][0] += fmaxf(acc[tm][tn][0] + bb.x, 0.f);
                        s[tn][1] += fmaxf(acc[tm][tn][1] + bb.y, 0.f);
                        s[tn][2] += fmaxf(acc[tm][tn][2] + bb.z, 0.f);
                        s[tn][3] += fmaxf(acc[tm][tn][3] + bb.w, 0.f);
                    }
                }
            }
#pragma unroll
            for (int tn = 0; tn < 4; tn++)
#pragma unroll
                for (int r = 0; r < 4; r++) {
                    float v = s[tn][r];
                    v += __shfl_xor(v, 1, 64);
                    v += __shfl_xor(v, 2, 64);
                    v += __shfl_xor(v, 4, 64);
                    v += __shfl_xor(v, 8, 64);
                    if (r16 == 0)
                        atomicAdd(&xg[b * 256 + n0w + tn * 16 + sub * 4 + r], v);
                }
        }
    }
}

// ---------------- f1 -> fc2 -> fc3 -> log_softmax ----------------
__global__ __launch_bounds__(256) void f_fused(
    const float* __restrict__ xg,
    const float* __restrict__ f1w, const float* __restrict__ f1b,
    const float* __restrict__ fc2w, const float* __restrict__ fc2b,
    const float* __restrict__ fc3w, const float* __restrict__ fc3b,
    float* __restrict__ out)
{
    const int b = blockIdx.x, tid = threadIdx.x;
    __shared__ float xa[256], xb[256], lg[10], red[2];
    xa[tid] = xg[b * 256 + tid];
    __syncthreads();
    {
        const float4* wr = (const float4*)(f1w + (size_t)tid * 256);
        float a = f1b[tid];
#pragma unroll
        for (int k4 = 0; k4 < 64; k4++) {
            float4 w4 = wr[k4];
            a += w4.x * xa[k4 * 4 + 0] + w4.y * xa[k4 * 4 + 1]
               + w4.z * xa[k4 * 4 + 2] + w4.w * xa[k4 * 4 + 3];
        }
        xb[tid] = a > 0.f ? a : 0.f;
    }
    __syncthreads();
    {
        const float4* wr = (const float4*)(fc2w + (size_t)tid * 256);
        float a = fc2b[tid];
#pragma unroll
        for (int k4 = 0; k4 < 64; k4++) {
            float4 w4 = wr[k4];
            a += w4.x * xb[k4 * 4 + 0] + w4.y * xb[k4 * 4 + 1]
               + w4.z * xb[k4 * 4 + 2] + w4.w * xb[k4 * 4 + 3];
        }
        __syncthreads();
        xa[tid] = a > 0.f ? a : 0.f;
    }
    __syncthreads();
    if (tid < 10) {
        const float4* wr = (const float4*)(fc3w + (size_t)tid * 256);
        float a = fc3b[tid];
#pragma unroll
        for (int k4 = 0; k4 < 64; k4++) {
            float4 w4 = wr[k4];
            a += w4.x * xa[k4 * 4 + 0] + w4.y * xa[k4 * 4 + 1]
               + w4.z * xa[k4 * 4 + 2] + w4.w * xa[k4 * 4 + 3];
        }
        lg[tid] = a;
    }
    __syncthreads();
    if (tid == 0) {
        float mx = lg[0];
        for (int o = 1; o < 10; o++) mx = lg[o] > mx ? lg[o] : mx;
        float ssum = 0.f;
        for (int o = 0; o < 10; o++) ssum += expf(lg[o] - mx);
        red[0] = mx;
        red[1] = logf(ssum);
    }
    __syncthreads();
    if (tid < 10) out[b * 10 + tid] = lg[tid] - red[0] - red[1];
}

// ---------------- launcher ----------------
extern "C" void kernel_launch(void* const* d_in, const int* in_sizes, int n_in,
                              void* d_out, int out_size, void* d_ws, size_t ws_size,
                              hipStream_t stream)
{
    const float* img  = (const float*)d_in[0];
    const float* qst  = (const float*)d_in[1];
    const float* cw1  = (const float*)d_in[2];
    const float* cb1  = (const float*)d_in[3];
    const float* bg1  = (const float*)d_in[4];
    const float* bb1  = (const float*)d_in[5];
    const float* cw2  = (const float*)d_in[6];
    const float* cb2  = (const float*)d_in[7];
    const float* bg2  = (const float*)d_in[8];
    const float* bb2  = (const float*)d_in[9];
    const float* cw3  = (const float*)d_in[10];
    const float* cb3  = (const float*)d_in[11];
    const float* bg3  = (const float*)d_in[12];
    const float* bb3  = (const float*)d_in[13];
    const float* cw4  = (const float*)d_in[14];
    const float* cb4  = (const float*)d_in[15];
    const float* bg4  = (const float*)d_in[16];
    const float* bb4  = (const float*)d_in[17];
    const float* g1w  = (const float*)d_in[18];
    const float* g1b  = (const float*)d_in[19];
    const float* g2w  = (const float*)d_in[20];
    const float* g2b  = (const float*)d_in[21];
    const float* g3w  = (const float*)d_in[22];
    const float* g3b  = (const float*)d_in[23];
    const float* g4w  = (const float*)d_in[24];
    const float* g4b  = (const float*)d_in[25];
    const float* f1w  = (const float*)d_in[26];
    const float* f1b  = (const float*)d_in[27];
    const float* fc2w = (const float*)d_in[28];
    const float* fc2b = (const float*)d_in[29];
    const float* fc3w = (const float*)d_in[30];
    const float* fc3b = (const float*)d_in[31];
    float* out = (float*)d_out;

    float* ws    = (float*)d_ws;
    float* stats = ws;                        // 192
    float* xg    = ws + 192;                  // 131072
    float* scsh  = ws + 131264;               // 192
    u16*   wfrag = (u16*)(ws + 131456);       // 196608 u16 (region: 196608 floats)
    float* y1    = ws + 328064;               // 19,660,800  [b][1600][24]
    float* y2    = ws + 19988864;             // 4,915,200   [b][400][24]
    float* y3    = ws + 24904064;             // 1,228,800   [b][100][24]
    float* y4    = ws + 26132864;             // 307,200     [b][25][24]
    u16*   u_bf  = (u16*)(ws + 26440064);     // 3,276,800 u16
    u16*   v_bf  = (u16*)(ws + 28078464);     // 3,276,800 u16
    float* wt1   = ws + 29716864;             // 648
    float* wtc   = ws + 29717512;             // 15552

    hipMemsetAsync(stats, 0, (size_t)131264 * sizeof(float), stream);

    w_prep<<<768, 256, 0, stream>>>(g2w, g3w, g4w, wfrag);
    wc_prep<<<64, 256, 0, stream>>>(cw1, cw2, cw3, cw4, wt1, wtc);

    conv1_t<<<2048, 256, 0, stream>>>(img, wt1, cb1, y1, stats);
    bn_fin<<<1, 32, 0, stream>>>(stats, bg1, bb1, 1.f / 819200.f, scsh);

    convN<40, 20, 10><<<1024, 256, 0, stream>>>(y1, scsh, wtc, cb2, y2, stats + 48);
    bn_fin<<<1, 32, 0, stream>>>(stats + 48, bg2, bb2, 1.f / 204800.f, scsh + 48);

    convN<20, 10, 10><<<512, 256, 0, stream>>>(y2, scsh + 48, wtc + 5184, cb3, y3, stats + 96);
    bn_fin<<<1, 32, 0, stream>>>(stats + 96, bg3, bb3, 1.f / 51200.f, scsh + 96);

    convN<10, 5, 5><<<512, 256, 0, stream>>>(y3, scsh + 96, wtc + 10368, cb4, y4, stats + 144);
    bn_fin<<<1, 32, 0, stream>>>(stats + 144, bg4, bb4, 1.f / 12800.f, scsh + 144);

    uv_kernel<<<512, 256, 0, stream>>>(y4, scsh + 144, qst, g1w, g1b, u_bf, v_bf);

    g_fused<<<2560, 256, 0, stream>>>(u_bf, v_bf, wfrag, g2b, g3b, g4b, xg);

    f_fused<<<512, 256, 0, stream>>>(xg, f1w, f1b, fc2w, fc2b, fc3w, fc3b, out);
}

// Round 5
// 702.977 us; speedup vs baseline: 6.9492x; 1.1393x over previous
//
#include <hip/hip_runtime.h>
#include <math.h>

// ---------------- problem constants ----------------
#define MB    512
#define FS    24
#define QDIM  11
#define OBJ   25
#define HID   256

typedef unsigned short u16;
typedef __attribute__((ext_vector_type(8))) __bf16 bf16x8;
typedef __attribute__((ext_vector_type(4))) float f32x4;

__device__ __forceinline__ float bf2f(u16 h) {
    return __uint_as_float(((unsigned int)h) << 16);
}
__device__ __forceinline__ u16 f2bf(float f) {
    unsigned int u = __float_as_uint(f);
    return (u16)((u + 0x7FFFu + ((u >> 16) & 1u)) >> 16);
}

// ---------------- conv weight prep ----------------
__global__ __launch_bounds__(256) void wc_prep(
    const float* __restrict__ cw1, const float* __restrict__ cw2,
    const float* __restrict__ cw3, const float* __restrict__ cw4,
    float* __restrict__ wt1, float* __restrict__ wtc)
{
    int idx = blockIdx.x * 256 + threadIdx.x;
    if (idx < 648) {
        int k = idx / 24, oc = idx % 24;
        wt1[idx] = cw1[oc * 27 + k];
    } else if (idx < 648 + 15552) {
        int t = idx - 648;
        int l = t / 5184, r = t % 5184;
        int j = r % 4, oc = (r / 4) % 24, g = (r / 96) % 6, kk = r / 576;
        const float* w = (l == 0) ? cw2 : ((l == 1) ? cw3 : cw4);
        wtc[t] = w[oc * 216 + (g * 4 + j) * 9 + kk];
    }
}

// ---------------- conv1: img NCHW -> y1 channel-last, + fused BN stats ----------------
__global__ __launch_bounds__(256) void conv1_t(
    const float* __restrict__ img, const float* __restrict__ wt1,
    const float* __restrict__ bias, float* __restrict__ yout,
    float* __restrict__ stats)
{
    __shared__ float tile[3 * 21 * 85];
    __shared__ float part[48];
    const int tid = threadIdx.x;
    const int b   = blockIdx.x >> 2;
    const int y0  = (blockIdx.x & 3) * 10;
    const int iy_base = 2 * y0 - 1;
    for (int e = tid; e < 3 * 21 * 85; e += 256) {
        int ixt = e % 85; int rem = e / 85;
        int iyl = rem % 21; int ic = rem / 21;
        int iy = iy_base + iyl, ix = ixt - 1;
        float v = 0.f;
        if ((unsigned)iy < 80u && (unsigned)ix < 80u)
            v = img[((size_t)(b * 3 + ic) * 80 + iy) * 80 + ix];
        tile[e] = v;
    }
    if (tid < 48) part[tid] = 0.f;
    __syncthreads();

    float rsum[24], rsq[24];
#pragma unroll
    for (int oc = 0; oc < 24; oc++) { rsum[oc] = 0.f; rsq[oc] = 0.f; }

#pragma unroll 1
    for (int pp = 0; pp < 2; pp++) {
        const int pxl = tid + pp * 256;
        const bool active = pxl < 400;
        const int pxc = active ? pxl : 0;
        const int yl = pxc / 40, x = pxc % 40;
        float acc[24];
#pragma unroll
        for (int oc = 0; oc < 24; oc++) acc[oc] = bias[oc];
#pragma unroll 1
        for (int ic = 0; ic < 3; ic++) {
#pragma unroll 1
            for (int ky = 0; ky < 3; ky++) {
#pragma unroll 1
                for (int kx = 0; kx < 3; kx++) {
                    const int k = (ic * 3 + ky) * 3 + kx;
                    float xin = tile[ic * 1785 + (2 * yl + ky) * 85 + (2 * x + kx)];
                    const float4* wrow = (const float4*)&wt1[k * 24];
#pragma unroll
                    for (int g = 0; g < 6; g++) {
                        float4 wv = wrow[g];
                        acc[g * 4 + 0] = fmaf(xin, wv.x, acc[g * 4 + 0]);
                        acc[g * 4 + 1] = fmaf(xin, wv.y, acc[g * 4 + 1]);
                        acc[g * 4 + 2] = fmaf(xin, wv.z, acc[g * 4 + 2]);
                        acc[g * 4 + 3] = fmaf(xin, wv.w, acc[g * 4 + 3]);
                    }
                }
            }
        }
#pragma unroll
        for (int oc = 0; oc < 24; oc++)
            acc[oc] = active ? fmaxf(acc[oc], 0.f) : 0.f;
        if (active) {
            float* op = &yout[((size_t)b * 1600 + (y0 + yl) * 40 + x) * 24];
#pragma unroll
            for (int g = 0; g < 6; g++)
                *(float4*)&op[g * 4] = make_float4(acc[g * 4], acc[g * 4 + 1],
                                                   acc[g * 4 + 2], acc[g * 4 + 3]);
        }
#pragma unroll
        for (int oc = 0; oc < 24; oc++) {
            rsum[oc] += acc[oc];
            rsq[oc]  += acc[oc] * acc[oc];
        }
    }
#pragma unroll
    for (int oc = 0; oc < 24; oc++) {
        float a = rsum[oc], q = rsq[oc];
#pragma unroll
        for (int off = 1; off < 64; off <<= 1) {
            a += __shfl_xor(a, off, 64);
            q += __shfl_xor(q, off, 64);
        }
        if ((tid & 63) == 0) { atomicAdd(&part[oc], a); atomicAdd(&part[24 + oc], q); }
    }
    __syncthreads();
    if (tid < 48) atomicAdd(&stats[tid], part[tid]);
}

// ---------------- generic conv 24->24, channel-last, bf16 LDS tile (stride-28 halves),
//                  BN folded on read, fp32 compute, + fused BN stats ----------------
template<int HIN, int HOUT, int YT>
__global__ __launch_bounds__(256) void convN(
    const float* __restrict__ yin,
    const float* __restrict__ scsh,
    const float* __restrict__ wtc,
    const float* __restrict__ bias,
    float* __restrict__ yout,
    float* __restrict__ stats)
{
    constexpr int ROWS  = 2 * YT + 1;
    constexpr int R     = 2 * HOUT + 3;
    constexpr int TSZ   = ROWS * R * 28;     // halves; 28*2=56B row stride (8B-aligned)
    constexpr int NPX   = HOUT * HOUT;
    constexpr int TILES = HOUT / YT;
    __shared__ __align__(16) u16 tile[TSZ];
    __shared__ float part[48];
    const int tid = threadIdx.x;
    const int b   = (TILES == 1) ? blockIdx.x : (int)(blockIdx.x / TILES);
    const int y0  = (TILES == 1) ? 0 : (int)(blockIdx.x % TILES) * YT;
    const int iy_base = 2 * y0 - 1;

    for (int e = tid; e < TSZ; e += 256) {
        int ic = e % 28; int rem = e / 28;
        int ixt = rem % R; int iyl = rem / R;
        int iy = iy_base + iyl, ix = ixt - 1;
        float v = 0.f;
        if (ic < 24 && (unsigned)iy < (unsigned)HIN && (unsigned)ix < (unsigned)HIN)
            v = yin[((size_t)b * HIN * HIN + iy * HIN + ix) * 24 + ic] * scsh[ic] + scsh[24 + ic];
        tile[e] = f2bf(v);
    }
    if (tid < 48) part[tid] = 0.f;
    __syncthreads();

    const bool active = tid < YT * HOUT;
    const int pxc = active ? tid : 0;
    const int yl = pxc / HOUT, x = pxc % HOUT;

    float acc[24];
#pragma unroll
    for (int oc = 0; oc < 24; oc++) acc[oc] = bias[oc];

#pragma unroll 1
    for (int ky = 0; ky < 3; ky++) {
#pragma unroll 1
        for (int kx = 0; kx < 3; kx++) {
            const int kk = ky * 3 + kx;
            const u16* trow = &tile[((2 * yl + ky) * R + (2 * x + kx)) * 28];
            const float4* wrow = (const float4*)&wtc[kk * 576];
#pragma unroll
            for (int g = 0; g < 6; g++) {
                ushort4 xr = *(const ushort4*)&trow[g * 4];
                float x0 = bf2f(xr.x), x1 = bf2f(xr.y);
                float x2 = bf2f(xr.z), x3 = bf2f(xr.w);
#pragma unroll
                for (int oc = 0; oc < 24; oc++) {
                    float4 wv = wrow[g * 24 + oc];
                    acc[oc] = fmaf(x0, wv.x, acc[oc]);
                    acc[oc] = fmaf(x1, wv.y, acc[oc]);
                    acc[oc] = fmaf(x2, wv.z, acc[oc]);
                    acc[oc] = fmaf(x3, wv.w, acc[oc]);
                }
            }
        }
    }
#pragma unroll
    for (int oc = 0; oc < 24; oc++)
        acc[oc] = active ? fmaxf(acc[oc], 0.f) : 0.f;
    if (active) {
        const int px = (y0 + yl) * HOUT + x;
        float* op = &yout[((size_t)b * NPX + px) * 24];
#pragma unroll
        for (int g = 0; g < 6; g++)
            *(float4*)&op[g * 4] = make_float4(acc[g * 4], acc[g * 4 + 1],
                                               acc[g * 4 + 2], acc[g * 4 + 3]);
    }
#pragma unroll
    for (int oc = 0; oc < 24; oc++) {
        float a = acc[oc], q = acc[oc] * acc[oc];
#pragma unroll
        for (int off = 1; off < 64; off <<= 1) {
            a += __shfl_xor(a, off, 64);
            q += __shfl_xor(q, off, 64);
        }
        if ((tid & 63) == 0) { atomicAdd(&part[oc], a); atomicAdd(&part[24 + oc], q); }
    }
    __syncthreads();
    if (tid < 48) atomicAdd(&stats[tid], part[tid]);
}

// ---------------- BN finalize ----------------
__global__ void bn_fin(const float* __restrict__ st, const float* __restrict__ gam,
                       const float* __restrict__ bet, float invN, float* __restrict__ scsh)
{
    int c = threadIdx.x;
    if (c < 24) {
        float m   = st[c] * invN;
        float var = st[24 + c] * invN - m * m;
        float inv = gam[c] * rsqrtf(var + 1e-5f);
        scsh[c]      = inv;
        scsh[24 + c] = bet[c] - m * inv;
    }
}

// ---------------- w_prep: per-lane MFMA A-fragment image of g2w/g3w/g4w ----------------
__global__ __launch_bounds__(256) void w_prep(
    const float* __restrict__ g2w, const float* __restrict__ g3w,
    const float* __restrict__ g4w, u16* __restrict__ wfrag)
{
    int idx = blockIdx.x * 256 + threadIdx.x;   // 196608 total
    int jj = idx & 7;
    int lane = (idx >> 3) & 63;
    int tn = (idx >> 9) & 15;
    int c = (idx >> 13) & 7;
    int l = idx >> 16;
    const float* W = (l == 0) ? g2w : ((l == 1) ? g3w : g4w);
    int n = tn * 16 + (lane & 15);
    int k = c * 32 + (lane >> 4) * 8 + jj;
    wfrag[idx] = f2bf(W[n * 256 + k]);
}

// ---------------- u/v precompute for g1 (bf16 output) ----------------
__global__ __launch_bounds__(256) void uv_kernel(
    const float* __restrict__ y4t, const float* __restrict__ scsh,
    const float* __restrict__ qst, const float* __restrict__ g1w,
    const float* __restrict__ g1b, u16* __restrict__ u, u16* __restrict__ v)
{
    int b = blockIdx.x, tid = threadIdx.x;
    __shared__ float xf[650];
    __shared__ float qv[11];
    for (int e = tid; e < 650; e += 256) {
        int o = e / 26, c = e % 26;
        float val;
        if (c < 24)      val = y4t[b * 600 + o * 24 + c] * scsh[c] + scsh[24 + c];
        else if (c == 24) val = (float)(o / 5 - 2) * 0.5f;
        else              val = (float)(o % 5 - 2) * 0.5f;
        xf[e] = val;
    }
    if (tid < 11) qv[tid] = qst[tid * MB + b];
    __syncthreads();
    const int n = tid;
    float wrow[63];
#pragma unroll
    for (int c = 0; c < 63; c++) wrow[c] = g1w[n * 63 + c];
    float qsum = g1b[n];
#pragma unroll
    for (int j = 0; j < 11; j++) qsum += wrow[52 + j] * qv[j];
    for (int o = 0; o < 25; o++) {
        float uu = 0.f, vv = qsum;
#pragma unroll
        for (int c = 0; c < 26; c++) {
            uu += wrow[c]      * xf[o * 26 + c];
            vv += wrow[26 + c] * xf[o * 26 + c];
        }
        u[(b * 25 + o) * 256 + n] = f2bf(uu);
        v[(b * 25 + o) * 256 + n] = f2bf(vv);
    }
}

// ---------------- fused g2/g3/g4 + pair-sum, bf16 MFMA, weights direct-from-global ----------------
__global__ __launch_bounds__(256, 2) void g_fused(
    const u16* __restrict__ u_bf, const u16* __restrict__ v_bf,
    const u16* __restrict__ wfrag,
    const float* __restrict__ b2, const float* __restrict__ b3, const float* __restrict__ b4,
    float* __restrict__ xg)
{
    __shared__ u16 hS[32768];   // 128 x 256 halves, XOR-swizzled 8-half granules
    const int tid  = threadIdx.x;
    const int b    = blockIdx.x / 5;
    const int p0   = (blockIdx.x % 5) * 128;
    const int lane = tid & 63, wave = tid >> 6;
    const int r16  = lane & 15, sub = lane >> 4;
    const int n0w  = wave * 64;

    const u16* wfL = wfrag + (size_t)(wave * 4) * 512 + (size_t)lane * 8;

    bf16x8 wcur[4], wnxt[4];
#pragma unroll
    for (int tn = 0; tn < 4; tn++)
        wcur[tn] = *(const bf16x8*)&wfL[(size_t)tn * 512];
#pragma unroll
    for (int tn = 0; tn < 4; tn++) wnxt[tn] = wcur[tn];

    {
        const int m = tid & 127, half = tid >> 7;
        const int p = p0 + m;
        if (p < 625) {
            const int oi = p % 25, ok = p / 25;
            const uint4* up = (const uint4*)(u_bf + (size_t)(b * 25 + oi) * 256);
            const uint4* vp = (const uint4*)(v_bf + (size_t)(b * 25 + ok) * 256);
#pragma unroll
            for (int gi = 0; gi < 16; gi++) {
                const int g = half * 16 + gi;
                uint4 ua = up[g], va = vp[g];
                const u16* uh = (const u16*)&ua;
                const u16* vh = (const u16*)&va;
                u16 o[8];
#pragma unroll
                for (int i = 0; i < 8; i++) {
                    float f = bf2f(uh[i]) + bf2f(vh[i]);
                    f = f > 0.f ? f : 0.f;
                    o[i] = f2bf(f);
                }
                *(uint4*)&hS[m * 256 + ((g ^ (m & 7)) * 8)] = *(uint4*)o;
            }
        } else {
            uint4 z = make_uint4(0, 0, 0, 0);
#pragma unroll
            for (int gi = 0; gi < 16; gi++) {
                const int g = half * 16 + gi;
                *(uint4*)&hS[m * 256 + ((g ^ (m & 7)) * 8)] = z;
            }
        }
    }

#pragma unroll 1
    for (int l = 0; l < 3; l++) {
        f32x4 acc[8][4];
#pragma unroll
        for (int tm = 0; tm < 8; tm++)
#pragma unroll
            for (int tn = 0; tn < 4; tn++)
                acc[tm][tn] = (f32x4)(0.f);

        __syncthreads();

#pragma unroll 1
        for (int kb = 0; kb < 8; kb++) {
            const int s = l * 8 + kb;
            if (s < 23) {
#pragma unroll
                for (int tn = 0; tn < 4; tn++)
                    wnxt[tn] = *(const bf16x8*)&wfL[((size_t)(s + 1) * 16 + tn) * 512];
            }
            bf16x8 bfr[8];
            const int g = kb * 4 + sub;
#pragma unroll
            for (int tm = 0; tm < 8; tm++) {
                const int m = tm * 16 + r16;
                bfr[tm] = *(const bf16x8*)&hS[m * 256 + ((g ^ (m & 7)) * 8)];
            }
#pragma unroll
            for (int tm = 0; tm < 8; tm++)
#pragma unroll
                for (int tn = 0; tn < 4; tn++)
                    acc[tm][tn] = __builtin_amdgcn_mfma_f32_16x16x32_bf16(
                        wcur[tn], bfr[tm], acc[tm][tn], 0, 0, 0);
#pragma unroll
            for (int tn = 0; tn < 4; tn++) wcur[tn] = wnxt[tn];
        }
        __syncthreads();

        const float* bl = (l == 0) ? b2 : ((l == 1) ? b3 : b4);
        if (l < 2) {
#pragma unroll
            for (int tn = 0; tn < 4; tn++) {
                const int n0 = n0w + tn * 16 + sub * 4;
                const float4 bb = *(const float4*)&bl[n0];
                const int gg = n0 >> 3;
                const int sh = (sub & 1) * 4;
#pragma unroll
                for (int tm = 0; tm < 8; tm++) {
                    const int m = tm * 16 + r16;
                    u16 o[4];
                    o[0] = f2bf(fmaxf(acc[tm][tn][0] + bb.x, 0.f));
                    o[1] = f2bf(fmaxf(acc[tm][tn][1] + bb.y, 0.f));
                    o[2] = f2bf(fmaxf(acc[tm][tn][2] + bb.z, 0.f));
                    o[3] = f2bf(fmaxf(acc[tm][tn][3] + bb.w, 0.f));
                    *(ushort4*)&hS[m * 256 + ((gg ^ (m & 7)) * 8) + sh] = *(ushort4*)o;
                }
            }
        } else {
            float s[4][4];
#pragma unroll
            for (int tn = 0; tn < 4; tn++)
#pragma unroll
                for (int r = 0; r < 4; r++) s[tn][r] = 0.f;
#pragma unroll
            for (int tn = 0; tn < 4; tn++) {
                const int n0 = n0w + tn * 16 + sub * 4;
                const float4 bb = *(const float4*)&bl[n0];
#pragma unroll
                for (int tm = 0; tm < 8; tm++) {
                    const int m = tm * 16 + r16;
                    if (p0 + m < 625) {
                        s[tn][0] += fmaxf(acc[tm][tn][0] + bb.x, 0.f);
                        s[tn][1] += fmaxf(acc[tm][tn][1] + bb.y, 0.f);
                        s[tn][2] += fmaxf(acc[tm][tn][2] + bb.z, 0.f);
                        s[tn][3] += fmaxf(acc[tm][tn][3] + bb.w, 0.f);
                    }
                }
            }
#pragma unroll
            for (int tn = 0; tn < 4; tn++)
#pragma unroll
                for (int r = 0; r < 4; r++) {
                    float v = s[tn][r];
                    v += __shfl_xor(v, 1, 64);
                    v += __shfl_xor(v, 2, 64);
                    v += __shfl_xor(v, 4, 64);
                    v += __shfl_xor(v, 8, 64);
                    if (r16 == 0)
                        atomicAdd(&xg[b * 256 + n0w + tn * 16 + sub * 4 + r], v);
                }
        }
    }
}

// ---------------- f1 -> fc2 -> fc3 -> log_softmax ----------------
__global__ __launch_bounds__(256) void f_fused(
    const float* __restrict__ xg,
    const float* __restrict__ f1w, const float* __restrict__ f1b,
    const float* __restrict__ fc2w, const float* __restrict__ fc2b,
    const float* __restrict__ fc3w, const float* __restrict__ fc3b,
    float* __restrict__ out)
{
    const int b = blockIdx.x, tid = threadIdx.x;
    __shared__ float xa[256], xb[256], lg[10], red[2];
    xa[tid] = xg[b * 256 + tid];
    __syncthreads();
    {
        const float4* wr = (const float4*)(f1w + (size_t)tid * 256);
        float a = f1b[tid];
#pragma unroll
        for (int k4 = 0; k4 < 64; k4++) {
            float4 w4 = wr[k4];
            a += w4.x * xa[k4 * 4 + 0] + w4.y * xa[k4 * 4 + 1]
               + w4.z * xa[k4 * 4 + 2] + w4.w * xa[k4 * 4 + 3];
        }
        xb[tid] = a > 0.f ? a : 0.f;
    }
    __syncthreads();
    {
        const float4* wr = (const float4*)(fc2w + (size_t)tid * 256);
        float a = fc2b[tid];
#pragma unroll
        for (int k4 = 0; k4 < 64; k4++) {
            float4 w4 = wr[k4];
            a += w4.x * xb[k4 * 4 + 0] + w4.y * xb[k4 * 4 + 1]
               + w4.z * xb[k4 * 4 + 2] + w4.w * xb[k4 * 4 + 3];
        }
        __syncthreads();
        xa[tid] = a > 0.f ? a : 0.f;
    }
    __syncthreads();
    if (tid < 10) {
        const float4* wr = (const float4*)(fc3w + (size_t)tid * 256);
        float a = fc3b[tid];
#pragma unroll
        for (int k4 = 0; k4 < 64; k4++) {
            float4 w4 = wr[k4];
            a += w4.x * xa[k4 * 4 + 0] + w4.y * xa[k4 * 4 + 1]
               + w4.z * xa[k4 * 4 + 2] + w4.w * xa[k4 * 4 + 3];
        }
        lg[tid] = a;
    }
    __syncthreads();
    if (tid == 0) {
        float mx = lg[0];
        for (int o = 1; o < 10; o++) mx = lg[o] > mx ? lg[o] : mx;
        float ssum = 0.f;
        for (int o = 0; o < 10; o++) ssum += expf(lg[o] - mx);
        red[0] = mx;
        red[1] = logf(ssum);
    }
    __syncthreads();
    if (tid < 10) out[b * 10 + tid] = lg[tid] - red[0] - red[1];
}

// ---------------- launcher ----------------
extern "C" void kernel_launch(void* const* d_in, const int* in_sizes, int n_in,
                              void* d_out, int out_size, void* d_ws, size_t ws_size,
                              hipStream_t stream)
{
    const float* img  = (const float*)d_in[0];
    const float* qst  = (const float*)d_in[1];
    const float* cw1  = (const float*)d_in[2];
    const float* cb1  = (const float*)d_in[3];
    const float* bg1  = (const float*)d_in[4];
    const float* bb1  = (const float*)d_in[5];
    const float* cw2  = (const float*)d_in[6];
    const float* cb2  = (const float*)d_in[7];
    const float* bg2  = (const float*)d_in[8];
    const float* bb2  = (const float*)d_in[9];
    const float* cw3  = (const float*)d_in[10];
    const float* cb3  = (const float*)d_in[11];
    const float* bg3  = (const float*)d_in[12];
    const float* bb3  = (const float*)d_in[13];
    const float* cw4  = (const float*)d_in[14];
    const float* cb4  = (const float*)d_in[15];
    const float* bg4  = (const float*)d_in[16];
    const float* bb4  = (const float*)d_in[17];
    const float* g1w  = (const float*)d_in[18];
    const float* g1b  = (const float*)d_in[19];
    const float* g2w  = (const float*)d_in[20];
    const float* g2b  = (const float*)d_in[21];
    const float* g3w  = (const float*)d_in[22];
    const float* g3b  = (const float*)d_in[23];
    const float* g4w  = (const float*)d_in[24];
    const float* g4b  = (const float*)d_in[25];
    const float* f1w  = (const float*)d_in[26];
    const float* f1b  = (const float*)d_in[27];
    const float* fc2w = (const float*)d_in[28];
    const float* fc2b = (const float*)d_in[29];
    const float* fc3w = (const float*)d_in[30];
    const float* fc3b = (const float*)d_in[31];
    float* out = (float*)d_out;

    float* ws    = (float*)d_ws;
    float* stats = ws;                        // 192
    float* xg    = ws + 192;                  // 131072
    float* scsh  = ws + 131264;               // 192
    u16*   wfrag = (u16*)(ws + 131456);       // 196608 u16
    float* y1    = ws + 328064;               // 19,660,800  [b][1600][24]
    float* y2    = ws + 19988864;             // 4,915,200   [b][400][24]
    float* y3    = ws + 24904064;             // 1,228,800   [b][100][24]
    float* y4    = ws + 26132864;             // 307,200     [b][25][24]
    u16*   u_bf  = (u16*)(ws + 26440064);     // 3,276,800 u16
    u16*   v_bf  = (u16*)(ws + 28078464);     // 3,276,800 u16
    float* wt1   = ws + 29716864;             // 648
    float* wtc   = ws + 29717512;             // 15552

    hipMemsetAsync(stats, 0, (size_t)131264 * sizeof(float), stream);

    w_prep<<<768, 256, 0, stream>>>(g2w, g3w, g4w, wfrag);
    wc_prep<<<64, 256, 0, stream>>>(cw1, cw2, cw3, cw4, wt1, wtc);

    conv1_t<<<2048, 256, 0, stream>>>(img, wt1, cb1, y1, stats);
    bn_fin<<<1, 32, 0, stream>>>(stats, bg1, bb1, 1.f / 819200.f, scsh);

    convN<40, 20, 10><<<1024, 256, 0, stream>>>(y1, scsh, wtc, cb2, y2, stats + 48);
    bn_fin<<<1, 32, 0, stream>>>(stats + 48, bg2, bb2, 1.f / 204800.f, scsh + 48);

    convN<20, 10, 10><<<512, 256, 0, stream>>>(y2, scsh + 48, wtc + 5184, cb3, y3, stats + 96);
    bn_fin<<<1, 32, 0, stream>>>(stats + 96, bg3, bb3, 1.f / 51200.f, scsh + 96);

    convN<10, 5, 5><<<512, 256, 0, stream>>>(y3, scsh + 96, wtc + 10368, cb4, y4, stats + 144);
    bn_fin<<<1, 32, 0, stream>>>(stats + 144, bg4, bb4, 1.f / 12800.f, scsh + 144);

    uv_kernel<<<512, 256, 0, stream>>>(y4, scsh + 144, qst, g1w, g1b, u_bf, v_bf);

    g_fused<<<2560, 256, 0, stream>>>(u_bf, v_bf, wfrag, g2b, g3b, g4b, xg);

    f_fused<<<512, 256, 0, stream>>>(xg, f1w, f1b, fc2w, fc2b, fc3w, fc3b, out);
}

// Round 6
// 683.688 us; speedup vs baseline: 7.1453x; 1.0282x over previous
//
#include <hip/hip_runtime.h>
#include <math.h>

// ---------------- problem constants ----------------
#define MB    512
#define FS    24
#define QDIM  11
#define OBJ   25
#define HID   256

typedef unsigned short u16;
typedef __attribute__((ext_vector_type(8))) __bf16 bf16x8;
typedef __attribute__((ext_vector_type(4))) float f32x4;

__device__ __forceinline__ float bf2f(u16 h) {
    return __uint_as_float(((unsigned int)h) << 16);
}
__device__ __forceinline__ u16 f2bf(float f) {
    unsigned int u = __float_as_uint(f);
    return (u16)((u + 0x7FFFu + ((u >> 16) & 1u)) >> 16);
}

// ---------------- combined prep: g-weight MFMA image + conv weight transposes ----------------
// blocks 0..767: wfrag (196608 u16); blocks 768..831: wt1 (648) + wtc (15552)
__global__ __launch_bounds__(256) void prep_all(
    const float* __restrict__ g2w, const float* __restrict__ g3w,
    const float* __restrict__ g4w, u16* __restrict__ wfrag,
    const float* __restrict__ cw1, const float* __restrict__ cw2,
    const float* __restrict__ cw3, const float* __restrict__ cw4,
    float* __restrict__ wt1, float* __restrict__ wtc)
{
    if (blockIdx.x < 768) {
        int idx = blockIdx.x * 256 + threadIdx.x;   // 196608 total
        int jj = idx & 7;
        int lane = (idx >> 3) & 63;
        int tn = (idx >> 9) & 15;
        int c = (idx >> 13) & 7;
        int l = idx >> 16;
        const float* W = (l == 0) ? g2w : ((l == 1) ? g3w : g4w);
        int n = tn * 16 + (lane & 15);
        int k = c * 32 + (lane >> 4) * 8 + jj;
        wfrag[idx] = f2bf(W[n * 256 + k]);
    } else {
        int idx = (blockIdx.x - 768) * 256 + threadIdx.x;
        if (idx < 648) {
            int k = idx / 24, oc = idx % 24;
            wt1[idx] = cw1[oc * 27 + k];
        } else if (idx < 648 + 15552) {
            int t = idx - 648;
            int l = t / 5184, r = t % 5184;
            int j = r % 4, oc = (r / 4) % 24, g = (r / 96) % 6, kk = r / 576;
            const float* w = (l == 0) ? cw2 : ((l == 1) ? cw3 : cw4);
            wtc[t] = w[oc * 216 + (g * 4 + j) * 9 + kk];
        }
    }
}

// ---------------- conv1: img NCHW -> y1 channel-last, LDS weights, + fused BN stats ----------------
__global__ __launch_bounds__(256) void conv1_t(
    const float* __restrict__ img, const float* __restrict__ wt1,
    const float* __restrict__ bias, float* __restrict__ yout,
    float* __restrict__ stats)
{
    __shared__ float tile[3 * 21 * 85];
    __shared__ float wS[648];
    __shared__ float part[48];
    const int tid = threadIdx.x;
    const int b   = blockIdx.x >> 2;
    const int y0  = (blockIdx.x & 3) * 10;
    const int iy_base = 2 * y0 - 1;
    for (int e = tid; e < 648; e += 256) wS[e] = wt1[e];
    for (int e = tid; e < 3 * 21 * 85; e += 256) {
        int ixt = e % 85; int rem = e / 85;
        int iyl = rem % 21; int ic = rem / 21;
        int iy = iy_base + iyl, ix = ixt - 1;
        float v = 0.f;
        if ((unsigned)iy < 80u && (unsigned)ix < 80u)
            v = img[((size_t)(b * 3 + ic) * 80 + iy) * 80 + ix];
        tile[e] = v;
    }
    if (tid < 48) part[tid] = 0.f;
    __syncthreads();

    float rsum[24], rsq[24];
#pragma unroll
    for (int oc = 0; oc < 24; oc++) { rsum[oc] = 0.f; rsq[oc] = 0.f; }

#pragma unroll 1
    for (int pp = 0; pp < 2; pp++) {
        const int pxl = tid + pp * 256;
        const bool active = pxl < 400;
        const int pxc = active ? pxl : 0;
        const int yl = pxc / 40, x = pxc % 40;
        float acc[24];
#pragma unroll
        for (int oc = 0; oc < 24; oc++) acc[oc] = bias[oc];
#pragma unroll 1
        for (int ic = 0; ic < 3; ic++) {
#pragma unroll 1
            for (int ky = 0; ky < 3; ky++) {
#pragma unroll 1
                for (int kx = 0; kx < 3; kx++) {
                    const int k = (ic * 3 + ky) * 3 + kx;
                    float xin = tile[ic * 1785 + (2 * yl + ky) * 85 + (2 * x + kx)];
                    const float4* wrow = (const float4*)&wS[k * 24];
#pragma unroll
                    for (int g = 0; g < 6; g++) {
                        float4 wv = wrow[g];
                        acc[g * 4 + 0] = fmaf(xin, wv.x, acc[g * 4 + 0]);
                        acc[g * 4 + 1] = fmaf(xin, wv.y, acc[g * 4 + 1]);
                        acc[g * 4 + 2] = fmaf(xin, wv.z, acc[g * 4 + 2]);
                        acc[g * 4 + 3] = fmaf(xin, wv.w, acc[g * 4 + 3]);
                    }
                }
            }
        }
#pragma unroll
        for (int oc = 0; oc < 24; oc++)
            acc[oc] = active ? fmaxf(acc[oc], 0.f) : 0.f;
        if (active) {
            float* op = &yout[((size_t)b * 1600 + (y0 + yl) * 40 + x) * 24];
#pragma unroll
            for (int g = 0; g < 6; g++)
                *(float4*)&op[g * 4] = make_float4(acc[g * 4], acc[g * 4 + 1],
                                                   acc[g * 4 + 2], acc[g * 4 + 3]);
        }
#pragma unroll
        for (int oc = 0; oc < 24; oc++) {
            rsum[oc] += acc[oc];
            rsq[oc]  += acc[oc] * acc[oc];
        }
    }
#pragma unroll
    for (int oc = 0; oc < 24; oc++) {
        float a = rsum[oc], q = rsq[oc];
#pragma unroll
        for (int off = 1; off < 64; off <<= 1) {
            a += __shfl_xor(a, off, 64);
            q += __shfl_xor(q, off, 64);
        }
        if ((tid & 63) == 0) { atomicAdd(&part[oc], a); atomicAdd(&part[24 + oc], q); }
    }
    __syncthreads();
    if (tid < 48) atomicAdd(&stats[tid], part[tid]);
}

// ---------------- generic conv 24->24, channel-last, bf16 LDS tile, LDS weights,
//                  BN(prev) computed in-kernel from stats, + fused BN stats ----------------
template<int HIN, int HOUT, int YT>
__global__ __launch_bounds__(256) void convN(
    const float* __restrict__ yin,
    const float* __restrict__ stp,   // prev-layer raw stats (48)
    const float* __restrict__ gam, const float* __restrict__ bet, float invN,
    const float* __restrict__ wtc,
    const float* __restrict__ bias,
    float* __restrict__ yout,
    float* __restrict__ stats)
{
    constexpr int ROWS  = 2 * YT + 1;
    constexpr int R     = 2 * HOUT + 3;
    constexpr int TSZ   = ROWS * R * 28;
    constexpr int NPX   = HOUT * HOUT;
    constexpr int TILES = HOUT / YT;
    __shared__ __align__(16) u16 tile[TSZ];
    __shared__ float wS[5184];
    __shared__ float scW[48];
    __shared__ float part[48];
    const int tid = threadIdx.x;
    const int b   = (TILES == 1) ? blockIdx.x : (int)(blockIdx.x / TILES);
    const int y0  = (TILES == 1) ? 0 : (int)(blockIdx.x % TILES) * YT;
    const int iy_base = 2 * y0 - 1;

    if (tid < 24) {
        float m   = stp[tid] * invN;
        float var = stp[24 + tid] * invN - m * m;
        float inv = gam[tid] * rsqrtf(var + 1e-5f);
        scW[tid]      = inv;
        scW[24 + tid] = bet[tid] - m * inv;
    }
    if (tid < 48) part[tid] = 0.f;
    for (int e = tid; e < 5184; e += 256) wS[e] = wtc[e];
    __syncthreads();   // scW ready

    for (int e = tid; e < TSZ; e += 256) {
        int ic = e % 28; int rem = e / 28;
        int ixt = rem % R; int iyl = rem / R;
        int iy = iy_base + iyl, ix = ixt - 1;
        float v = 0.f;
        if (ic < 24 && (unsigned)iy < (unsigned)HIN && (unsigned)ix < (unsigned)HIN)
            v = yin[((size_t)b * HIN * HIN + iy * HIN + ix) * 24 + ic] * scW[ic] + scW[24 + ic];
        tile[e] = f2bf(v);
    }
    __syncthreads();

    const bool active = tid < YT * HOUT;
    const int pxc = active ? tid : 0;
    const int yl = pxc / HOUT, x = pxc % HOUT;

    float acc[24];
#pragma unroll
    for (int oc = 0; oc < 24; oc++) acc[oc] = bias[oc];

#pragma unroll 1
    for (int ky = 0; ky < 3; ky++) {
#pragma unroll 1
        for (int kx = 0; kx < 3; kx++) {
            const int kk = ky * 3 + kx;
            const u16* trow = &tile[((2 * yl + ky) * R + (2 * x + kx)) * 28];
            const float4* wrow = (const float4*)&wS[kk * 576];
#pragma unroll
            for (int g = 0; g < 6; g++) {
                ushort4 xr = *(const ushort4*)&trow[g * 4];
                float x0 = bf2f(xr.x), x1 = bf2f(xr.y);
                float x2 = bf2f(xr.z), x3 = bf2f(xr.w);
#pragma unroll
                for (int oc = 0; oc < 24; oc++) {
                    float4 wv = wrow[g * 24 + oc];
                    acc[oc] = fmaf(x0, wv.x, acc[oc]);
                    acc[oc] = fmaf(x1, wv.y, acc[oc]);
                    acc[oc] = fmaf(x2, wv.z, acc[oc]);
                    acc[oc] = fmaf(x3, wv.w, acc[oc]);
                }
            }
        }
    }
#pragma unroll
    for (int oc = 0; oc < 24; oc++)
        acc[oc] = active ? fmaxf(acc[oc], 0.f) : 0.f;
    if (active) {
        const int px = (y0 + yl) * HOUT + x;
        float* op = &yout[((size_t)b * NPX + px) * 24];
#pragma unroll
        for (int g = 0; g < 6; g++)
            *(float4*)&op[g * 4] = make_float4(acc[g * 4], acc[g * 4 + 1],
                                               acc[g * 4 + 2], acc[g * 4 + 3]);
    }
#pragma unroll
    for (int oc = 0; oc < 24; oc++) {
        float a = acc[oc], q = acc[oc] * acc[oc];
#pragma unroll
        for (int off = 1; off < 64; off <<= 1) {
            a += __shfl_xor(a, off, 64);
            q += __shfl_xor(q, off, 64);
        }
        if ((tid & 63) == 0) { atomicAdd(&part[oc], a); atomicAdd(&part[24 + oc], q); }
    }
    __syncthreads();
    if (tid < 48) atomicAdd(&stats[tid], part[tid]);
}

// ---------------- u/v precompute for g1 (bf16 output), BN4 computed in-kernel ----------------
__global__ __launch_bounds__(256) void uv_kernel(
    const float* __restrict__ y4t,
    const float* __restrict__ stp, const float* __restrict__ gam,
    const float* __restrict__ bet, float invN,
    const float* __restrict__ qst, const float* __restrict__ g1w,
    const float* __restrict__ g1b, u16* __restrict__ u, u16* __restrict__ v)
{
    int b = blockIdx.x, tid = threadIdx.x;
    __shared__ float xf[650];
    __shared__ float qv[11];
    __shared__ float scW[48];
    if (tid < 24) {
        float m   = stp[tid] * invN;
        float var = stp[24 + tid] * invN - m * m;
        float inv = gam[tid] * rsqrtf(var + 1e-5f);
        scW[tid]      = inv;
        scW[24 + tid] = bet[tid] - m * inv;
    }
    __syncthreads();
    for (int e = tid; e < 650; e += 256) {
        int o = e / 26, c = e % 26;
        float val;
        if (c < 24)      val = y4t[b * 600 + o * 24 + c] * scW[c] + scW[24 + c];
        else if (c == 24) val = (float)(o / 5 - 2) * 0.5f;
        else              val = (float)(o % 5 - 2) * 0.5f;
        xf[e] = val;
    }
    if (tid < 11) qv[tid] = qst[tid * MB + b];
    __syncthreads();
    const int n = tid;
    float wrow[63];
#pragma unroll
    for (int c = 0; c < 63; c++) wrow[c] = g1w[n * 63 + c];
    float qsum = g1b[n];
#pragma unroll
    for (int j = 0; j < 11; j++) qsum += wrow[52 + j] * qv[j];
    for (int o = 0; o < 25; o++) {
        float uu = 0.f, vv = qsum;
#pragma unroll
        for (int c = 0; c < 26; c++) {
            uu += wrow[c]      * xf[o * 26 + c];
            vv += wrow[26 + c] * xf[o * 26 + c];
        }
        u[(b * 25 + o) * 256 + n] = f2bf(uu);
        v[(b * 25 + o) * 256 + n] = f2bf(vv);
    }
}

// ---------------- fused g2/g3/g4 + pair-sum, bf16 MFMA, weights direct-from-global ----------------
__global__ __launch_bounds__(256, 2) void g_fused(
    const u16* __restrict__ u_bf, const u16* __restrict__ v_bf,
    const u16* __restrict__ wfrag,
    const float* __restrict__ b2, const float* __restrict__ b3, const float* __restrict__ b4,
    float* __restrict__ xg)
{
    __shared__ u16 hS[32768];   // 128 x 256 halves, XOR-swizzled 8-half granules
    const int tid  = threadIdx.x;
    const int b    = blockIdx.x / 5;
    const int p0   = (blockIdx.x % 5) * 128;
    const int lane = tid & 63, wave = tid >> 6;
    const int r16  = lane & 15, sub = lane >> 4;
    const int n0w  = wave * 64;

    const u16* wfL = wfrag + (size_t)(wave * 4) * 512 + (size_t)lane * 8;

    bf16x8 wcur[4], wnxt[4];
#pragma unroll
    for (int tn = 0; tn < 4; tn++)
        wcur[tn] = *(const bf16x8*)&wfL[(size_t)tn * 512];
#pragma unroll
    for (int tn = 0; tn < 4; tn++) wnxt[tn] = wcur[tn];

    {
        const int m = tid & 127, half = tid >> 7;
        const int p = p0 + m;
        if (p < 625) {
            const int oi = p % 25, ok = p / 25;
            const uint4* up = (const uint4*)(u_bf + (size_t)(b * 25 + oi) * 256);
            const uint4* vp = (const uint4*)(v_bf + (size_t)(b * 25 + ok) * 256);
#pragma unroll
            for (int gi = 0; gi < 16; gi++) {
                const int g = half * 16 + gi;
                uint4 ua = up[g], va = vp[g];
                const u16* uh = (const u16*)&ua;
                const u16* vh = (const u16*)&va;
                u16 o[8];
#pragma unroll
                for (int i = 0; i < 8; i++) {
                    float f = bf2f(uh[i]) + bf2f(vh[i]);
                    f = f > 0.f ? f : 0.f;
                    o[i] = f2bf(f);
                }
                *(uint4*)&hS[m * 256 + ((g ^ (m & 7)) * 8)] = *(uint4*)o;
            }
        } else {
            uint4 z = make_uint4(0, 0, 0, 0);
#pragma unroll
            for (int gi = 0; gi < 16; gi++) {
                const int g = half * 16 + gi;
                *(uint4*)&hS[m * 256 + ((g ^ (m & 7)) * 8)] = z;
            }
        }
    }

#pragma unroll 1
    for (int l = 0; l < 3; l++) {
        f32x4 acc[8][4];
#pragma unroll
        for (int tm = 0; tm < 8; tm++)
#pragma unroll
            for (int tn = 0; tn < 4; tn++)
                acc[tm][tn] = (f32x4)(0.f);

        __syncthreads();

#pragma unroll 1
        for (int kb = 0; kb < 8; kb++) {
            const int s = l * 8 + kb;
            if (s < 23) {
#pragma unroll
                for (int tn = 0; tn < 4; tn++)
                    wnxt[tn] = *(const bf16x8*)&wfL[((size_t)(s + 1) * 16 + tn) * 512];
            }
            bf16x8 bfr[8];
            const int g = kb * 4 + sub;
#pragma unroll
            for (int tm = 0; tm < 8; tm++) {
                const int m = tm * 16 + r16;
                bfr[tm] = *(const bf16x8*)&hS[m * 256 + ((g ^ (m & 7)) * 8)];
            }
#pragma unroll
            for (int tm = 0; tm < 8; tm++)
#pragma unroll
                for (int tn = 0; tn < 4; tn++)
                    acc[tm][tn] = __builtin_amdgcn_mfma_f32_16x16x32_bf16(
                        wcur[tn], bfr[tm], acc[tm][tn], 0, 0, 0);
#pragma unroll
            for (int tn = 0; tn < 4; tn++) wcur[tn] = wnxt[tn];
        }
        __syncthreads();

        const float* bl = (l == 0) ? b2 : ((l == 1) ? b3 : b4);
        if (l < 2) {
#pragma unroll
            for (int tn = 0; tn < 4; tn++) {
                const int n0 = n0w + tn * 16 + sub * 4;
                const float4 bb = *(const float4*)&bl[n0];
                const int gg = n0 >> 3;
                const int sh = (sub & 1) * 4;
#pragma unroll
                for (int tm = 0; tm < 8; tm++) {
                    const int m = tm * 16 + r16;
                    u16 o[4];
                    o[0] = f2bf(fmaxf(acc[tm][tn][0] + bb.x, 0.f));
                    o[1] = f2bf(fmaxf(acc[tm][tn][1] + bb.y, 0.f));
                    o[2] = f2bf(fmaxf(acc[tm][tn][2] + bb.z, 0.f));
                    o[3] = f2bf(fmaxf(acc[tm][tn][3] + bb.w, 0.f));
                    *(ushort4*)&hS[m * 256 + ((gg ^ (m & 7)) * 8) + sh] = *(ushort4*)o;
                }
            }
        } else {
            float s[4][4];
#pragma unroll
            for (int tn = 0; tn < 4; tn++)
#pragma unroll
                for (int r = 0; r < 4; r++) s[tn][r] = 0.f;
#pragma unroll
            for (int tn = 0; tn < 4; tn++) {
                const int n0 = n0w + tn * 16 + sub * 4;
                const float4 bb = *(const float4*)&bl[n0];
#pragma unroll
                for (int tm = 0; tm < 8; tm++) {
                    const int m = tm * 16 + r16;
                    if (p0 + m < 625) {
                        s[tn][0] += fmaxf(acc[tm][tn][0] + bb.x, 0.f);
                        s[tn][1] += fmaxf(acc[tm][tn][1] + bb.y, 0.f);
                        s[tn][2] += fmaxf(acc[tm][tn][2] + bb.z, 0.f);
                        s[tn][3] += fmaxf(acc[tm][tn][3] + bb.w, 0.f);
                    }
                }
            }
#pragma unroll
            for (int tn = 0; tn < 4; tn++)
#pragma unroll
                for (int r = 0; r < 4; r++) {
                    float v = s[tn][r];
                    v += __shfl_xor(v, 1, 64);
                    v += __shfl_xor(v, 2, 64);
                    v += __shfl_xor(v, 4, 64);
                    v += __shfl_xor(v, 8, 64);
                    if (r16 == 0)
                        atomicAdd(&xg[b * 256 + n0w + tn * 16 + sub * 4 + r], v);
                }
        }
    }
}

// ---------------- f1 -> fc2 -> fc3 -> log_softmax ----------------
__global__ __launch_bounds__(256) void f_fused(
    const float* __restrict__ xg,
    const float* __restrict__ f1w, const float* __restrict__ f1b,
    const float* __restrict__ fc2w, const float* __restrict__ fc2b,
    const float* __restrict__ fc3w, const float* __restrict__ fc3b,
    float* __restrict__ out)
{
    const int b = blockIdx.x, tid = threadIdx.x;
    __shared__ float xa[256], xb[256], lg[10], red[2];
    xa[tid] = xg[b * 256 + tid];
    __syncthreads();
    {
        const float4* wr = (const float4*)(f1w + (size_t)tid * 256);
        float a = f1b[tid];
#pragma unroll
        for (int k4 = 0; k4 < 64; k4++) {
            float4 w4 = wr[k4];
            a += w4.x * xa[k4 * 4 + 0] + w4.y * xa[k4 * 4 + 1]
               + w4.z * xa[k4 * 4 + 2] + w4.w * xa[k4 * 4 + 3];
        }
        xb[tid] = a > 0.f ? a : 0.f;
    }
    __syncthreads();
    {
        const float4* wr = (const float4*)(fc2w + (size_t)tid * 256);
        float a = fc2b[tid];
#pragma unroll
        for (int k4 = 0; k4 < 64; k4++) {
            float4 w4 = wr[k4];
            a += w4.x * xb[k4 * 4 + 0] + w4.y * xb[k4 * 4 + 1]
               + w4.z * xb[k4 * 4 + 2] + w4.w * xb[k4 * 4 + 3];
        }
        __syncthreads();
        xa[tid] = a > 0.f ? a : 0.f;
    }
    __syncthreads();
    if (tid < 10) {
        const float4* wr = (const float4*)(fc3w + (size_t)tid * 256);
        float a = fc3b[tid];
#pragma unroll
        for (int k4 = 0; k4 < 64; k4++) {
            float4 w4 = wr[k4];
            a += w4.x * xa[k4 * 4 + 0] + w4.y * xa[k4 * 4 + 1]
               + w4.z * xa[k4 * 4 + 2] + w4.w * xa[k4 * 4 + 3];
        }
        lg[tid] = a;
    }
    __syncthreads();
    if (tid == 0) {
        float mx = lg[0];
        for (int o = 1; o < 10; o++) mx = lg[o] > mx ? lg[o] : mx;
        float ssum = 0.f;
        for (int o = 0; o < 10; o++) ssum += expf(lg[o] - mx);
        red[0] = mx;
        red[1] = logf(ssum);
    }
    __syncthreads();
    if (tid < 10) out[b * 10 + tid] = lg[tid] - red[0] - red[1];
}

// ---------------- launcher ----------------
extern "C" void kernel_launch(void* const* d_in, const int* in_sizes, int n_in,
                              void* d_out, int out_size, void* d_ws, size_t ws_size,
                              hipStream_t stream)
{
    const float* img  = (const float*)d_in[0];
    const float* qst  = (const float*)d_in[1];
    const float* cw1  = (const float*)d_in[2];
    const float* cb1  = (const float*)d_in[3];
    const float* bg1  = (const float*)d_in[4];
    const float* bb1  = (const float*)d_in[5];
    const float* cw2  = (const float*)d_in[6];
    const float* cb2  = (const float*)d_in[7];
    const float* bg2  = (const float*)d_in[8];
    const float* bb2  = (const float*)d_in[9];
    const float* cw3  = (const float*)d_in[10];
    const float* cb3  = (const float*)d_in[11];
    const float* bg3  = (const float*)d_in[12];
    const float* bb3  = (const float*)d_in[13];
    const float* cw4  = (const float*)d_in[14];
    const float* cb4  = (const float*)d_in[15];
    const float* bg4  = (const float*)d_in[16];
    const float* bb4  = (const float*)d_in[17];
    const float* g1w  = (const float*)d_in[18];
    const float* g1b  = (const float*)d_in[19];
    const float* g2w  = (const float*)d_in[20];
    const float* g2b  = (const float*)d_in[21];
    const float* g3w  = (const float*)d_in[22];
    const float* g3b  = (const float*)d_in[23];
    const float* g4w  = (const float*)d_in[24];
    const float* g4b  = (const float*)d_in[25];
    const float* f1w  = (const float*)d_in[26];
    const float* f1b  = (const float*)d_in[27];
    const float* fc2w = (const float*)d_in[28];
    const float* fc2b = (const float*)d_in[29];
    const float* fc3w = (const float*)d_in[30];
    const float* fc3b = (const float*)d_in[31];
    float* out = (float*)d_out;

    float* ws    = (float*)d_ws;
    float* stats = ws;                        // 192
    float* xg    = ws + 192;                  // 131072
    u16*   wfrag = (u16*)(ws + 131456);       // 196608 u16
    float* y1    = ws + 328064;               // 19,660,800  [b][1600][24]
    float* y2    = ws + 19988864;             // 4,915,200   [b][400][24]
    float* y3    = ws + 24904064;             // 1,228,800   [b][100][24]
    float* y4    = ws + 26132864;             // 307,200     [b][25][24]
    u16*   u_bf  = (u16*)(ws + 26440064);     // 3,276,800 u16
    u16*   v_bf  = (u16*)(ws + 28078464);     // 3,276,800 u16
    float* wt1   = ws + 29716864;             // 648
    float* wtc   = ws + 29717512;             // 15552

    hipMemsetAsync(stats, 0, (size_t)131264 * sizeof(float), stream);

    prep_all<<<832, 256, 0, stream>>>(g2w, g3w, g4w, wfrag,
                                      cw1, cw2, cw3, cw4, wt1, wtc);

    conv1_t<<<2048, 256, 0, stream>>>(img, wt1, cb1, y1, stats);

    convN<40, 20, 10><<<1024, 256, 0, stream>>>(y1, stats, bg1, bb1, 1.f / 819200.f,
                                                wtc, cb2, y2, stats + 48);
    convN<20, 10, 10><<<512, 256, 0, stream>>>(y2, stats + 48, bg2, bb2, 1.f / 204800.f,
                                               wtc + 5184, cb3, y3, stats + 96);
    convN<10, 5, 5><<<512, 256, 0, stream>>>(y3, stats + 96, bg3, bb3, 1.f / 51200.f,
                                             wtc + 10368, cb4, y4, stats + 144);

    uv_kernel<<<512, 256, 0, stream>>>(y4, stats + 144, bg4, bb4, 1.f / 12800.f,
                                       qst, g1w, g1b, u_bf, v_bf);

    g_fused<<<2560, 256, 0, stream>>>(u_bf, v_bf, wfrag, g2b, g3b, g4b, xg);

    f_fused<<<512, 256, 0, stream>>>(xg, f1w, f1b, fc2w, fc2b, fc3w, fc3b, out);
}

// Round 7
// 492.799 us; speedup vs baseline: 9.9131x; 1.3874x over previous
//
#include <hip/hip_runtime.h>
#include <math.h>

// ---------------- problem constants ----------------
#define MB    512
#define FS    24
#define QDIM  11
#define OBJ   25
#define HID   256

typedef unsigned short u16;
typedef __attribute__((ext_vector_type(8))) __bf16 bf16x8;
typedef __attribute__((ext_vector_type(4))) float f32x4;

__device__ __forceinline__ float bf2f(u16 h) {
    return __uint_as_float(((unsigned int)h) << 16);
}
__device__ __forceinline__ u16 f2bf(float f) {
    unsigned int u = __float_as_uint(f);
    return (u16)((u + 0x7FFFu + ((u >> 16) & 1u)) >> 16);
}

// ---------------- combined prep ----------------
// blocks 0..767: wfrag for g-GEMMs (196608 u16)
// blocks 768..878: wt1 (648 f32) + wcfrag (27648 u16)
// wcfrag[l][cell 9][oct 2][lane 64][j 8]: oc=oct*16+(lane&15), ic=(lane>>4)*8+j,
//   val = (oc<24 && ic<24) ? cw[oc][ic][ky][kx] : 0   (cell = ky*3+kx)
__global__ __launch_bounds__(256) void prep_all(
    const float* __restrict__ g2w, const float* __restrict__ g3w,
    const float* __restrict__ g4w, u16* __restrict__ wfrag,
    const float* __restrict__ cw1, const float* __restrict__ cw2,
    const float* __restrict__ cw3, const float* __restrict__ cw4,
    float* __restrict__ wt1, u16* __restrict__ wcfrag)
{
    if (blockIdx.x < 768) {
        int idx = blockIdx.x * 256 + threadIdx.x;   // 196608 total
        int jj = idx & 7;
        int lane = (idx >> 3) & 63;
        int tn = (idx >> 9) & 15;
        int c = (idx >> 13) & 7;
        int l = idx >> 16;
        const float* W = (l == 0) ? g2w : ((l == 1) ? g3w : g4w);
        int n = tn * 16 + (lane & 15);
        int k = c * 32 + (lane >> 4) * 8 + jj;
        wfrag[idx] = f2bf(W[n * 256 + k]);
    } else {
        int idx = (blockIdx.x - 768) * 256 + threadIdx.x;
        if (idx < 648) {
            int k = idx / 24, oc = idx % 24;
            wt1[idx] = cw1[oc * 27 + k];
        } else if (idx < 648 + 27648) {
            int t = idx - 648;
            int l = t / 9216, r = t % 9216;
            int cell = r / 1024, rr = r % 1024;
            int o = rr / 512, q = rr % 512;
            int lane = q / 8, j = q % 8;
            int oc = o * 16 + (lane & 15);
            int ic = (lane >> 4) * 8 + j;
            const float* w = (l == 0) ? cw2 : ((l == 1) ? cw3 : cw4);
            u16 v = 0;
            if (oc < 24 && ic < 24) v = f2bf(w[oc * 216 + ic * 9 + cell]);
            wcfrag[t] = v;
        }
    }
}

// ---------------- conv1: img NCHW -> y1 channel-last, LDS weights, + fused BN stats ----------------
__global__ __launch_bounds__(256) void conv1_t(
    const float* __restrict__ img, const float* __restrict__ wt1,
    const float* __restrict__ bias, float* __restrict__ yout,
    float* __restrict__ stats)
{
    __shared__ float tile[3 * 21 * 85];
    __shared__ float wS[648];
    __shared__ float part[48];
    const int tid = threadIdx.x;
    const int b   = blockIdx.x >> 2;
    const int y0  = (blockIdx.x & 3) * 10;
    const int iy_base = 2 * y0 - 1;
    for (int e = tid; e < 648; e += 256) wS[e] = wt1[e];
    for (int e = tid; e < 3 * 21 * 85; e += 256) {
        int ixt = e % 85; int rem = e / 85;
        int iyl = rem % 21; int ic = rem / 21;
        int iy = iy_base + iyl, ix = ixt - 1;
        float v = 0.f;
        if ((unsigned)iy < 80u && (unsigned)ix < 80u)
            v = img[((size_t)(b * 3 + ic) * 80 + iy) * 80 + ix];
        tile[e] = v;
    }
    if (tid < 48) part[tid] = 0.f;
    __syncthreads();

    float rsum[24], rsq[24];
#pragma unroll
    for (int oc = 0; oc < 24; oc++) { rsum[oc] = 0.f; rsq[oc] = 0.f; }

#pragma unroll 1
    for (int pp = 0; pp < 2; pp++) {
        const int pxl = tid + pp * 256;
        const bool active = pxl < 400;
        const int pxc = active ? pxl : 0;
        const int yl = pxc / 40, x = pxc % 40;
        float acc[24];
#pragma unroll
        for (int oc = 0; oc < 24; oc++) acc[oc] = bias[oc];
#pragma unroll 1
        for (int ic = 0; ic < 3; ic++) {
#pragma unroll 1
            for (int ky = 0; ky < 3; ky++) {
#pragma unroll 1
                for (int kx = 0; kx < 3; kx++) {
                    const int k = (ic * 3 + ky) * 3 + kx;
                    float xin = tile[ic * 1785 + (2 * yl + ky) * 85 + (2 * x + kx)];
                    const float4* wrow = (const float4*)&wS[k * 24];
#pragma unroll
                    for (int g = 0; g < 6; g++) {
                        float4 wv = wrow[g];
                        acc[g * 4 + 0] = fmaf(xin, wv.x, acc[g * 4 + 0]);
                        acc[g * 4 + 1] = fmaf(xin, wv.y, acc[g * 4 + 1]);
                        acc[g * 4 + 2] = fmaf(xin, wv.z, acc[g * 4 + 2]);
                        acc[g * 4 + 3] = fmaf(xin, wv.w, acc[g * 4 + 3]);
                    }
                }
            }
        }
#pragma unroll
        for (int oc = 0; oc < 24; oc++)
            acc[oc] = active ? fmaxf(acc[oc], 0.f) : 0.f;
        if (active) {
            float* op = &yout[((size_t)b * 1600 + (y0 + yl) * 40 + x) * 24];
#pragma unroll
            for (int g = 0; g < 6; g++)
                *(float4*)&op[g * 4] = make_float4(acc[g * 4], acc[g * 4 + 1],
                                                   acc[g * 4 + 2], acc[g * 4 + 3]);
        }
#pragma unroll
        for (int oc = 0; oc < 24; oc++) {
            rsum[oc] += acc[oc];
            rsq[oc]  += acc[oc] * acc[oc];
        }
    }
#pragma unroll
    for (int oc = 0; oc < 24; oc++) {
        float a = rsum[oc], q = rsq[oc];
#pragma unroll
        for (int off = 1; off < 64; off <<= 1) {
            a += __shfl_xor(a, off, 64);
            q += __shfl_xor(q, off, 64);
        }
        if ((tid & 63) == 0) { atomicAdd(&part[oc], a); atomicAdd(&part[24 + oc], q); }
    }
    __syncthreads();
    if (tid < 48) atomicAdd(&stats[tid], part[tid]);
}

// ---------------- MFMA conv 24->24 stride2 pad1, channel-last, BN(prev) folded on read,
//                  + fused bias/relu/store/BN-stats epilogue ----------------
// k-chunk = one (ky,kx) cell, ic padded 24->32 (weight rows 24..31 = 0; X quad3 lanes zeroed).
// A-operand = weight fragments (36 VGPRs, preloaded from wcfrag); B-operand = X read from
// channel-last bf16 LDS tile (stride 24 halves, one ds_read_b128 per m-tile per cell).
template<int HIN, int HOUT, int YT, int MT>
__global__ __launch_bounds__(256) void convM(
    const float* __restrict__ yin,
    const float* __restrict__ stp, const float* __restrict__ gam,
    const float* __restrict__ bet, float invN,
    const u16* __restrict__ wcf_g,
    const float* __restrict__ bias,
    float* __restrict__ yout, float* __restrict__ stats)
{
    constexpr int ROWS = 2 * YT + 1;
    constexpr int R    = 2 * HOUT + 1;
    constexpr int POS  = ROWS * R;
    constexpr int NPX  = HOUT * HOUT;
    constexpr int NPXB = YT * HOUT;
    constexpr int TILES = HOUT / YT;
    constexpr int MTPW = (MT + 3) / 4;
    __shared__ __align__(16) u16 tile[POS * 24 + 16];
    __shared__ float scW[48];
    __shared__ float part[48];
    const int tid  = threadIdx.x;
    const int b    = (TILES == 1) ? blockIdx.x : (int)(blockIdx.x / TILES);
    const int y0   = (TILES == 1) ? 0 : (int)(blockIdx.x % TILES) * YT;
    const int lane = tid & 63, wave = tid >> 6;
    const int r16  = lane & 15, quad = lane >> 4;

    if (tid < 24) {
        float m   = stp[tid] * invN;
        float var = stp[24 + tid] * invN - m * m;
        float inv = gam[tid] * rsqrtf(var + 1e-5f);
        scW[tid]      = inv;
        scW[24 + tid] = bet[tid] - m * inv;
    }
    if (tid < 48) part[tid] = 0.f;

    // weight A-fragments -> registers (per lane)
    bf16x8 wcf[9][2];
#pragma unroll
    for (int c = 0; c < 9; c++)
#pragma unroll
        for (int o = 0; o < 2; o++)
            wcf[c][o] = *(const bf16x8*)&wcf_g[((c * 2 + o) * 64 + lane) * 8];

    __syncthreads();   // scW ready

    // stage input tile (bf16, channel-last, BN-folded)
    const int iy_base = 2 * y0 - 1;
    for (int p = tid; p < POS; p += 256) {
        int iyl = p / R, ixt = p % R;
        int iy = iy_base + iyl, ix = ixt - 1;
        u16 hv[24];
        if ((unsigned)iy < (unsigned)HIN && (unsigned)ix < (unsigned)HIN) {
            const float* ip = &yin[((size_t)b * HIN * HIN + iy * HIN + ix) * 24];
#pragma unroll
            for (int c = 0; c < 24; c++)
                hv[c] = f2bf(ip[c] * scW[c] + scW[24 + c]);
        } else {
#pragma unroll
            for (int c = 0; c < 24; c++) hv[c] = 0;
        }
#pragma unroll
        for (int g = 0; g < 3; g++)
            *(uint4*)&tile[p * 24 + g * 8] = *(uint4*)&hv[g * 8];
    }
    __syncthreads();

    f32x4 acc[MTPW][2];
#pragma unroll
    for (int t = 0; t < MTPW; t++) {
        acc[t][0] = (f32x4)(0.f);
        acc[t][1] = (f32x4)(0.f);
    }

    int baseT[MTPW];
#pragma unroll
    for (int t = 0; t < MTPW; t++) {
        int mt = wave + t * 4;
        int pxl = mt * 16 + r16;
        if (pxl > NPXB - 1) pxl = NPXB - 1;
        baseT[t] = ((2 * (pxl / HOUT)) * R + 2 * (pxl % HOUT)) * 24 + quad * 8;
    }

#pragma unroll
    for (int ky = 0; ky < 3; ky++) {
#pragma unroll
        for (int kx = 0; kx < 3; kx++) {
            const int cell = ky * 3 + kx;
            const int coff = (ky * R + kx) * 24;
            bf16x8 xf[MTPW];
#pragma unroll
            for (int t = 0; t < MTPW; t++) {
                int mt = wave + t * 4;
                uint4 tmp = make_uint4(0, 0, 0, 0);
                if (mt < MT && quad < 3)
                    tmp = *(const uint4*)&tile[baseT[t] + coff];
                xf[t] = *(bf16x8*)&tmp;
            }
#pragma unroll
            for (int t = 0; t < MTPW; t++) {
                int mt = wave + t * 4;
                if (mt < MT) {
                    acc[t][0] = __builtin_amdgcn_mfma_f32_16x16x32_bf16(
                        wcf[cell][0], xf[t], acc[t][0], 0, 0, 0);
                    acc[t][1] = __builtin_amdgcn_mfma_f32_16x16x32_bf16(
                        wcf[cell][1], xf[t], acc[t][1], 0, 0, 0);
                }
            }
        }
    }

    // epilogue: bias + relu + store + stats
    float ss[2][4], qq[2][4];
#pragma unroll
    for (int o = 0; o < 2; o++)
#pragma unroll
        for (int r = 0; r < 4; r++) { ss[o][r] = 0.f; qq[o][r] = 0.f; }

#pragma unroll
    for (int t = 0; t < MTPW; t++) {
        int mt = wave + t * 4;
        if (mt >= MT) continue;
        int pxl = mt * 16 + r16;
        bool pv = pxl < NPXB;
        int pxi = y0 * HOUT + pxl;
#pragma unroll
        for (int o = 0; o < 2; o++) {
            int ocb = o * 16 + quad * 4;
            if (pv && ocb < 24) {
                float4 bb = *(const float4*)&bias[ocb];
                float v0 = fmaxf(acc[t][o][0] + bb.x, 0.f);
                float v1 = fmaxf(acc[t][o][1] + bb.y, 0.f);
                float v2 = fmaxf(acc[t][o][2] + bb.z, 0.f);
                float v3 = fmaxf(acc[t][o][3] + bb.w, 0.f);
                *(float4*)&yout[((size_t)b * NPX + pxi) * 24 + ocb] =
                    make_float4(v0, v1, v2, v3);
                ss[o][0] += v0; qq[o][0] += v0 * v0;
                ss[o][1] += v1; qq[o][1] += v1 * v1;
                ss[o][2] += v2; qq[o][2] += v2 * v2;
                ss[o][3] += v3; qq[o][3] += v3 * v3;
            }
        }
    }
#pragma unroll
    for (int o = 0; o < 2; o++) {
        int ocb = o * 16 + quad * 4;
#pragma unroll
        for (int r = 0; r < 4; r++) {
            float a = ss[o][r], q = qq[o][r];
            a += __shfl_xor(a, 1, 64); q += __shfl_xor(q, 1, 64);
            a += __shfl_xor(a, 2, 64); q += __shfl_xor(q, 2, 64);
            a += __shfl_xor(a, 4, 64); q += __shfl_xor(q, 4, 64);
            a += __shfl_xor(a, 8, 64); q += __shfl_xor(q, 8, 64);
            if (r16 == 0 && ocb < 24) {
                atomicAdd(&part[ocb + r], a);
                atomicAdd(&part[24 + ocb + r], q);
            }
        }
    }
    __syncthreads();
    if (tid < 48) atomicAdd(&stats[tid], part[tid]);
}

// ---------------- u/v precompute for g1 (bf16 output), BN4 computed in-kernel ----------------
__global__ __launch_bounds__(256) void uv_kernel(
    const float* __restrict__ y4t,
    const float* __restrict__ stp, const float* __restrict__ gam,
    const float* __restrict__ bet, float invN,
    const float* __restrict__ qst, const float* __restrict__ g1w,
    const float* __restrict__ g1b, u16* __restrict__ u, u16* __restrict__ v)
{
    int b = blockIdx.x, tid = threadIdx.x;
    __shared__ float xf[650];
    __shared__ float qv[11];
    __shared__ float scW[48];
    if (tid < 24) {
        float m   = stp[tid] * invN;
        float var = stp[24 + tid] * invN - m * m;
        float inv = gam[tid] * rsqrtf(var + 1e-5f);
        scW[tid]      = inv;
        scW[24 + tid] = bet[tid] - m * inv;
    }
    __syncthreads();
    for (int e = tid; e < 650; e += 256) {
        int o = e / 26, c = e % 26;
        float val;
        if (c < 24)      val = y4t[b * 600 + o * 24 + c] * scW[c] + scW[24 + c];
        else if (c == 24) val = (float)(o / 5 - 2) * 0.5f;
        else              val = (float)(o % 5 - 2) * 0.5f;
        xf[e] = val;
    }
    if (tid < 11) qv[tid] = qst[tid * MB + b];
    __syncthreads();
    const int n = tid;
    float wrow[63];
#pragma unroll
    for (int c = 0; c < 63; c++) wrow[c] = g1w[n * 63 + c];
    float qsum = g1b[n];
#pragma unroll
    for (int j = 0; j < 11; j++) qsum += wrow[52 + j] * qv[j];
    for (int o = 0; o < 25; o++) {
        float uu = 0.f, vv = qsum;
#pragma unroll
        for (int c = 0; c < 26; c++) {
            uu += wrow[c]      * xf[o * 26 + c];
            vv += wrow[26 + c] * xf[o * 26 + c];
        }
        u[(b * 25 + o) * 256 + n] = f2bf(uu);
        v[(b * 25 + o) * 256 + n] = f2bf(vv);
    }
}

// ---------------- fused g2/g3/g4 + pair-sum, bf16 MFMA, weights direct-from-global ----------------
__global__ __launch_bounds__(256, 2) void g_fused(
    const u16* __restrict__ u_bf, const u16* __restrict__ v_bf,
    const u16* __restrict__ wfrag,
    const float* __restrict__ b2, const float* __restrict__ b3, const float* __restrict__ b4,
    float* __restrict__ xg)
{
    __shared__ u16 hS[32768];   // 128 x 256 halves, XOR-swizzled 8-half granules
    const int tid  = threadIdx.x;
    const int b    = blockIdx.x / 5;
    const int p0   = (blockIdx.x % 5) * 128;
    const int lane = tid & 63, wave = tid >> 6;
    const int r16  = lane & 15, sub = lane >> 4;
    const int n0w  = wave * 64;

    const u16* wfL = wfrag + (size_t)(wave * 4) * 512 + (size_t)lane * 8;

    bf16x8 wcur[4], wnxt[4];
#pragma unroll
    for (int tn = 0; tn < 4; tn++)
        wcur[tn] = *(const bf16x8*)&wfL[(size_t)tn * 512];
#pragma unroll
    for (int tn = 0; tn < 4; tn++) wnxt[tn] = wcur[tn];

    {
        const int m = tid & 127, half = tid >> 7;
        const int p = p0 + m;
        if (p < 625) {
            const int oi = p % 25, ok = p / 25;
            const uint4* up = (const uint4*)(u_bf + (size_t)(b * 25 + oi) * 256);
            const uint4* vp = (const uint4*)(v_bf + (size_t)(b * 25 + ok) * 256);
#pragma unroll
            for (int gi = 0; gi < 16; gi++) {
                const int g = half * 16 + gi;
                uint4 ua = up[g], va = vp[g];
                const u16* uh = (const u16*)&ua;
                const u16* vh = (const u16*)&va;
                u16 o[8];
#pragma unroll
                for (int i = 0; i < 8; i++) {
                    float f = bf2f(uh[i]) + bf2f(vh[i]);
                    f = f > 0.f ? f : 0.f;
                    o[i] = f2bf(f);
                }
                *(uint4*)&hS[m * 256 + ((g ^ (m & 7)) * 8)] = *(uint4*)o;
            }
        } else {
            uint4 z = make_uint4(0, 0, 0, 0);
#pragma unroll
            for (int gi = 0; gi < 16; gi++) {
                const int g = half * 16 + gi;
                *(uint4*)&hS[m * 256 + ((g ^ (m & 7)) * 8)] = z;
            }
        }
    }

#pragma unroll 1
    for (int l = 0; l < 3; l++) {
        f32x4 acc[8][4];
#pragma unroll
        for (int tm = 0; tm < 8; tm++)
#pragma unroll
            for (int tn = 0; tn < 4; tn++)
                acc[tm][tn] = (f32x4)(0.f);

        __syncthreads();

#pragma unroll 1
        for (int kb = 0; kb < 8; kb++) {
            const int s = l * 8 + kb;
            if (s < 23) {
#pragma unroll
                for (int tn = 0; tn < 4; tn++)
                    wnxt[tn] = *(const bf16x8*)&wfL[((size_t)(s + 1) * 16 + tn) * 512];
            }
            bf16x8 bfr[8];
            const int g = kb * 4 + sub;
#pragma unroll
            for (int tm = 0; tm < 8; tm++) {
                const int m = tm * 16 + r16;
                bfr[tm] = *(const bf16x8*)&hS[m * 256 + ((g ^ (m & 7)) * 8)];
            }
#pragma unroll
            for (int tm = 0; tm < 8; tm++)
#pragma unroll
                for (int tn = 0; tn < 4; tn++)
                    acc[tm][tn] = __builtin_amdgcn_mfma_f32_16x16x32_bf16(
                        wcur[tn], bfr[tm], acc[tm][tn], 0, 0, 0);
#pragma unroll
            for (int tn = 0; tn < 4; tn++) wcur[tn] = wnxt[tn];
        }
        __syncthreads();

        const float* bl = (l == 0) ? b2 : ((l == 1) ? b3 : b4);
        if (l < 2) {
#pragma unroll
            for (int tn = 0; tn < 4; tn++) {
                const int n0 = n0w + tn * 16 + sub * 4;
                const float4 bb = *(const float4*)&bl[n0];
                const int gg = n0 >> 3;
                const int sh = (sub & 1) * 4;
#pragma unroll
                for (int tm = 0; tm < 8; tm++) {
                    const int m = tm * 16 + r16;
                    u16 o[4];
                    o[0] = f2bf(fmaxf(acc[tm][tn][0] + bb.x, 0.f));
                    o[1] = f2bf(fmaxf(acc[tm][tn][1] + bb.y, 0.f));
                    o[2] = f2bf(fmaxf(acc[tm][tn][2] + bb.z, 0.f));
                    o[3] = f2bf(fmaxf(acc[tm][tn][3] + bb.w, 0.f));
                    *(ushort4*)&hS[m * 256 + ((gg ^ (m & 7)) * 8) + sh] = *(ushort4*)o;
                }
            }
        } else {
            float s[4][4];
#pragma unroll
            for (int tn = 0; tn < 4; tn++)
#pragma unroll
                for (int r = 0; r < 4; r++) s[tn][r] = 0.f;
#pragma unroll
            for (int tn = 0; tn < 4; tn++) {
                const int n0 = n0w + tn * 16 + sub * 4;
                const float4 bb = *(const float4*)&bl[n0];
#pragma unroll
                for (int tm = 0; tm < 8; tm++) {
                    const int m = tm * 16 + r16;
                    if (p0 + m < 625) {
                        s[tn][0] += fmaxf(acc[tm][tn][0] + bb.x, 0.f);
                        s[tn][1] += fmaxf(acc[tm][tn][1] + bb.y, 0.f);
                        s[tn][2] += fmaxf(acc[tm][tn][2] + bb.z, 0.f);
                        s[tn][3] += fmaxf(acc[tm][tn][3] + bb.w, 0.f);
                    }
                }
            }
#pragma unroll
            for (int tn = 0; tn < 4; tn++)
#pragma unroll
                for (int r = 0; r < 4; r++) {
                    float v = s[tn][r];
                    v += __shfl_xor(v, 1, 64);
                    v += __shfl_xor(v, 2, 64);
                    v += __shfl_xor(v, 4, 64);
                    v += __shfl_xor(v, 8, 64);
                    if (r16 == 0)
                        atomicAdd(&xg[b * 256 + n0w + tn * 16 + sub * 4 + r], v);
                }
        }
    }
}

// ---------------- f1 -> fc2 -> fc3 -> log_softmax ----------------
__global__ __launch_bounds__(256) void f_fused(
    const float* __restrict__ xg,
    const float* __restrict__ f1w, const float* __restrict__ f1b,
    const float* __restrict__ fc2w, const float* __restrict__ fc2b,
    const float* __restrict__ fc3w, const float* __restrict__ fc3b,
    float* __restrict__ out)
{
    const int b = blockIdx.x, tid = threadIdx.x;
    __shared__ float xa[256], xb[256], lg[10], red[2];
    xa[tid] = xg[b * 256 + tid];
    __syncthreads();
    {
        const float4* wr = (const float4*)(f1w + (size_t)tid * 256);
        float a = f1b[tid];
#pragma unroll
        for (int k4 = 0; k4 < 64; k4++) {
            float4 w4 = wr[k4];
            a += w4.x * xa[k4 * 4 + 0] + w4.y * xa[k4 * 4 + 1]
               + w4.z * xa[k4 * 4 + 2] + w4.w * xa[k4 * 4 + 3];
        }
        xb[tid] = a > 0.f ? a : 0.f;
    }
    __syncthreads();
    {
        const float4* wr = (const float4*)(fc2w + (size_t)tid * 256);
        float a = fc2b[tid];
#pragma unroll
        for (int k4 = 0; k4 < 64; k4++) {
            float4 w4 = wr[k4];
            a += w4.x * xb[k4 * 4 + 0] + w4.y * xb[k4 * 4 + 1]
               + w4.z * xb[k4 * 4 + 2] + w4.w * xb[k4 * 4 + 3];
        }
        __syncthreads();
        xa[tid] = a > 0.f ? a : 0.f;
    }
    __syncthreads();
    if (tid < 10) {
        const float4* wr = (const float4*)(fc3w + (size_t)tid * 256);
        float a = fc3b[tid];
#pragma unroll
        for (int k4 = 0; k4 < 64; k4++) {
            float4 w4 = wr[k4];
            a += w4.x * xa[k4 * 4 + 0] + w4.y * xa[k4 * 4 + 1]
               + w4.z * xa[k4 * 4 + 2] + w4.w * xa[k4 * 4 + 3];
        }
        lg[tid] = a;
    }
    __syncthreads();
    if (tid == 0) {
        float mx = lg[0];
        for (int o = 1; o < 10; o++) mx = lg[o] > mx ? lg[o] : mx;
        float ssum = 0.f;
        for (int o = 0; o < 10; o++) ssum += expf(lg[o] - mx);
        red[0] = mx;
        red[1] = logf(ssum);
    }
    __syncthreads();
    if (tid < 10) out[b * 10 + tid] = lg[tid] - red[0] - red[1];
}

// ---------------- launcher ----------------
extern "C" void kernel_launch(void* const* d_in, const int* in_sizes, int n_in,
                              void* d_out, int out_size, void* d_ws, size_t ws_size,
                              hipStream_t stream)
{
    const float* img  = (const float*)d_in[0];
    const float* qst  = (const float*)d_in[1];
    const float* cw1  = (const float*)d_in[2];
    const float* cb1  = (const float*)d_in[3];
    const float* bg1  = (const float*)d_in[4];
    const float* bb1  = (const float*)d_in[5];
    const float* cw2  = (const float*)d_in[6];
    const float* cb2  = (const float*)d_in[7];
    const float* bg2  = (const float*)d_in[8];
    const float* bb2  = (const float*)d_in[9];
    const float* cw3  = (const float*)d_in[10];
    const float* cb3  = (const float*)d_in[11];
    const float* bg3  = (const float*)d_in[12];
    const float* bb3  = (const float*)d_in[13];
    const float* cw4  = (const float*)d_in[14];
    const float* cb4  = (const float*)d_in[15];
    const float* bg4  = (const float*)d_in[16];
    const float* bb4  = (const float*)d_in[17];
    const float* g1w  = (const float*)d_in[18];
    const float* g1b  = (const float*)d_in[19];
    const float* g2w  = (const float*)d_in[20];
    const float* g2b  = (const float*)d_in[21];
    const float* g3w  = (const float*)d_in[22];
    const float* g3b  = (const float*)d_in[23];
    const float* g4w  = (const float*)d_in[24];
    const float* g4b  = (const float*)d_in[25];
    const float* f1w  = (const float*)d_in[26];
    const float* f1b  = (const float*)d_in[27];
    const float* fc2w = (const float*)d_in[28];
    const float* fc2b = (const float*)d_in[29];
    const float* fc3w = (const float*)d_in[30];
    const float* fc3b = (const float*)d_in[31];
    float* out = (float*)d_out;

    float* ws    = (float*)d_ws;
    float* stats = ws;                        // 192
    float* xg    = ws + 192;                  // 131072
    u16*   wfrag = (u16*)(ws + 131456);       // 196608 u16
    float* y1    = ws + 328064;               // 19,660,800  [b][1600][24]
    float* y2    = ws + 19988864;             // 4,915,200   [b][400][24]
    float* y3    = ws + 24904064;             // 1,228,800   [b][100][24]
    float* y4    = ws + 26132864;             // 307,200     [b][25][24]
    u16*   u_bf  = (u16*)(ws + 26440064);     // 3,276,800 u16
    u16*   v_bf  = (u16*)(ws + 28078464);     // 3,276,800 u16
    float* wt1   = ws + 29716864;             // 648
    u16*   wcfrag = (u16*)(ws + 29717512);    // 27648 u16

    hipMemsetAsync(stats, 0, (size_t)131264 * sizeof(float), stream);

    prep_all<<<879, 256, 0, stream>>>(g2w, g3w, g4w, wfrag,
                                      cw1, cw2, cw3, cw4, wt1, wcfrag);

    conv1_t<<<2048, 256, 0, stream>>>(img, wt1, cb1, y1, stats);

    convM<40, 20, 4, 5><<<2560, 256, 0, stream>>>(
        y1, stats, bg1, bb1, 1.f / 819200.f, wcfrag, cb2, y2, stats + 48);
    convM<20, 10, 10, 7><<<512, 256, 0, stream>>>(
        y2, stats + 48, bg2, bb2, 1.f / 204800.f, wcfrag + 9216, cb3, y3, stats + 96);
    convM<10, 5, 5, 2><<<512, 256, 0, stream>>>(
        y3, stats + 96, bg3, bb3, 1.f / 51200.f, wcfrag + 18432, cb4, y4, stats + 144);

    uv_kernel<<<512, 256, 0, stream>>>(y4, stats + 144, bg4, bb4, 1.f / 12800.f,
                                       qst, g1w, g1b, u_bf, v_bf);

    g_fused<<<2560, 256, 0, stream>>>(u_bf, v_bf, wfrag, g2b, g3b, g4b, xg);

    f_fused<<<512, 256, 0, stream>>>(xg, f1w, f1b, fc2w, fc2b, fc3w, fc3b, out);
}